// Round 1
// baseline (11575.224 us; speedup 1.0000x reference)
//
#include <hip/hip_runtime.h>

#define N_NODES 100000
#define N_EDGES 1600000
#define F_IN_DIM 100
#define H_DIM 256
#define BN_DIM 128
#define N_LABELS 19
#define BN_EPS 1e-5f

// ---------------------------------------------------------------- degree
__global__ void deg_kernel(const int* __restrict__ dst, float* __restrict__ deg, int E) {
    int e = blockIdx.x * blockDim.x + threadIdx.x;
    if (e < E) atomicAdd(&deg[dst[e]], 1.0f);
}

__global__ void rsqrt_kernel(float* __restrict__ d, int n) {
    int i = blockIdx.x * blockDim.x + threadIdx.x;
    if (i < n) d[i] = rsqrtf(d[i] + 1.0f);
}

// ---------------------------------------------------------------- clip
__global__ void clip_kernel(const float* __restrict__ x, float* __restrict__ out, int total4) {
    int i = blockIdx.x * blockDim.x + threadIdx.x;
    if (i >= total4) return;
    float4 v = ((const float4*)x)[i];
    v.x = fminf(fmaxf(v.x, -0.4f), 0.4f);
    v.y = fminf(fmaxf(v.y, -0.4f), 0.4f);
    v.z = fminf(fmaxf(v.z, -0.4f), 0.4f);
    v.w = fminf(fmaxf(v.w, -0.4f), 0.4f);
    ((float4*)out)[i] = v;
}

// ---------------------------------------------------------------- GEMM
// C[M x Nout] = A[M x K] @ W[K x Nout]; optional bias (len Nout),
// optional per-row scale (applied after bias), optional relu.
// 64x64 tile, 256 threads, 4x4 micro-tile, BK=32.
__global__ __launch_bounds__(256) void gemm_kernel(
    const float* __restrict__ A, const float* __restrict__ W,
    const float* __restrict__ bias, const float* __restrict__ rowscale,
    float* __restrict__ C, int M, int K, int Nout, int relu)
{
    __shared__ float As[32][68];  // [k][m], +4 pad keeps 16B alignment
    __shared__ float Bs[32][64];  // [k][n]
    int tid = threadIdx.x;
    int tn = tid & 15, tm = tid >> 4;
    int rowBase = blockIdx.y * 64;
    int colBase = blockIdx.x * 64;
    float acc[4][4] = {};

    for (int k0 = 0; k0 < K; k0 += 32) {
        #pragma unroll
        for (int i = 0; i < 8; i++) {
            int lin = tid + i * 256;          // 2048 = 64 rows x 32 k
            int r = lin >> 5, c = lin & 31;
            int gr = rowBase + r, gc = k0 + c;
            float v = (gr < M && gc < K) ? A[(size_t)gr * K + gc] : 0.f;
            As[c][r] = v;
        }
        #pragma unroll
        for (int i = 0; i < 8; i++) {
            int lin = tid + i * 256;          // 2048 = 32 k x 64 n
            int kk = lin >> 6, nn = lin & 63;
            int gk = k0 + kk, gn = colBase + nn;
            float v = (gk < K && gn < Nout) ? W[(size_t)gk * Nout + gn] : 0.f;
            Bs[kk][nn] = v;
        }
        __syncthreads();
        #pragma unroll
        for (int k = 0; k < 32; k++) {
            float a[4], b[4];
            #pragma unroll
            for (int i = 0; i < 4; i++) a[i] = As[k][tm * 4 + i];
            #pragma unroll
            for (int j = 0; j < 4; j++) b[j] = Bs[k][tn * 4 + j];
            #pragma unroll
            for (int i = 0; i < 4; i++)
                #pragma unroll
                for (int j = 0; j < 4; j++)
                    acc[i][j] = fmaf(a[i], b[j], acc[i][j]);
        }
        __syncthreads();
    }

    #pragma unroll
    for (int i = 0; i < 4; i++) {
        int r = rowBase + tm * 4 + i;
        if (r >= M) continue;
        float rs = rowscale ? rowscale[r] : 1.f;
        #pragma unroll
        for (int j = 0; j < 4; j++) {
            int c = colBase + tn * 4 + j;
            if (c >= Nout) continue;
            float v = acc[i][j];
            if (bias) v += bias[c];
            v *= rs;
            if (relu) v = fmaxf(v, 0.f);
            C[(size_t)r * Nout + c] = v;
        }
    }
}

// ---------------------------------------------------------------- scatter
// agg[dst[e]] += xws[src[e]]   (xws already scaled by dinv[src] in GEMM epilogue)
__global__ void scatter_kernel(const float* __restrict__ xws,
                               const int* __restrict__ src,
                               const int* __restrict__ dst,
                               float* __restrict__ agg, int E, int F)
{
    unsigned idx = blockIdx.x * blockDim.x + threadIdx.x;
    int chunks = F >> 2;
    unsigned total = (unsigned)E * (unsigned)chunks;
    if (idx >= total) return;
    int e = idx / (unsigned)chunks;
    int c4 = (int)(idx - (unsigned)e * (unsigned)chunks) << 2;
    int s = src[e], d = dst[e];
    float4 v = *(const float4*)(xws + (size_t)s * F + c4);
    float* base = agg + (size_t)d * F + c4;
    atomicAdd(base + 0, v.x);
    atomicAdd(base + 1, v.y);
    atomicAdd(base + 2, v.z);
    atomicAdd(base + 3, v.w);
}

// ---------------------------------------------------------------- self-loop + bias + relu
// agg[i] = relu(dinv[i]*(agg[i] + xws[i]) + b)    (in place)
__global__ void selfloop_kernel(float* __restrict__ agg,
                                const float* __restrict__ xws,
                                const float* __restrict__ dinv,
                                const float* __restrict__ bias,
                                int total, int F)
{
    int idx = blockIdx.x * blockDim.x + threadIdx.x;
    if (idx >= total) return;
    int chunks = F >> 2;
    int i = idx / chunks;
    int c4 = (idx - i * chunks) << 2;
    float di = dinv[i];
    size_t off = (size_t)i * F + c4;
    float4 a = *(float4*)(agg + off);
    float4 xv = *(const float4*)(xws + off);
    float4 o;
    o.x = fmaxf(di * (a.x + xv.x) + bias[c4 + 0], 0.f);
    o.y = fmaxf(di * (a.y + xv.y) + bias[c4 + 1], 0.f);
    o.z = fmaxf(di * (a.z + xv.z) + bias[c4 + 2], 0.f);
    o.w = fmaxf(di * (a.w + xv.w) + bias[c4 + 3], 0.f);
    *(float4*)(agg + off) = o;
}

// ---------------------------------------------------------------- BN
__global__ void bn_stats_kernel(const float* __restrict__ h,
                                float* __restrict__ sum, float* __restrict__ sumsq, int Ntot)
{
    int c = threadIdx.x & 127;
    int rpb = blockDim.x >> 7;  // rows per block sweep = 2
    int r0 = blockIdx.x * rpb + (threadIdx.x >> 7);
    int stride = gridDim.x * rpb;
    float s = 0.f, ss = 0.f;
    for (int r = r0; r < Ntot; r += stride) {
        float v = h[(size_t)r * BN_DIM + c];
        s += v; ss += v * v;
    }
    __shared__ float ls[256], lss[256];
    ls[threadIdx.x] = s; lss[threadIdx.x] = ss;
    __syncthreads();
    if (threadIdx.x < 128) {
        s = ls[threadIdx.x] + ls[threadIdx.x + 128];
        ss = lss[threadIdx.x] + lss[threadIdx.x + 128];
        atomicAdd(&sum[c], s);
        atomicAdd(&sumsq[c], ss);
    }
}

__global__ void bn_finalize_kernel(const float* __restrict__ sum, const float* __restrict__ sumsq,
                                   const float* __restrict__ gamma, const float* __restrict__ beta,
                                   float* __restrict__ a, float* __restrict__ b, int Ntot)
{
    int c = threadIdx.x;
    float inv_n = 1.0f / (float)Ntot;
    float mu = sum[c] * inv_n;
    float var = sumsq[c] * inv_n - mu * mu;
    float ai = gamma[c] * rsqrtf(var + BN_EPS);
    a[c] = ai;
    b[c] = beta[c] - mu * ai;
}

__global__ void bn_apply_kernel(float* __restrict__ h,
                                const float* __restrict__ a, const float* __restrict__ b,
                                int total4)
{
    int i = blockIdx.x * blockDim.x + threadIdx.x;
    if (i >= total4) return;
    int c = (i & 31) << 2;  // 128/4 = 32 chunks per row
    float4 v = ((float4*)h)[i];
    v.x = fmaxf(v.x * a[c + 0] + b[c + 0], 0.f);
    v.y = fmaxf(v.y * a[c + 1] + b[c + 1], 0.f);
    v.z = fmaxf(v.z * a[c + 2] + b[c + 2], 0.f);
    v.w = fmaxf(v.w * a[c + 3] + b[c + 3], 0.f);
    ((float4*)h)[i] = v;
}

// ---------------------------------------------------------------- log_softmax
__global__ void logsoftmax_kernel(const float* __restrict__ logits, float* __restrict__ out, int Ntot)
{
    int r = blockIdx.x * blockDim.x + threadIdx.x;
    if (r >= Ntot) return;
    const float* p = logits + (size_t)r * N_LABELS;
    float m = p[0];
    #pragma unroll
    for (int j = 1; j < N_LABELS; j++) m = fmaxf(m, p[j]);
    float s = 0.f;
    #pragma unroll
    for (int j = 0; j < N_LABELS; j++) s += expf(p[j] - m);
    float lse = m + logf(s);
    float* o = out + (size_t)r * N_LABELS;
    #pragma unroll
    for (int j = 0; j < N_LABELS; j++) o[j] = p[j] - lse;
}

// ================================================================ launch
static inline void run_gemm(const float* A, const float* W, const float* bias,
                            const float* rowscale, float* C,
                            int M, int K, int Nout, int relu, hipStream_t stream)
{
    dim3 grid((Nout + 63) / 64, (M + 63) / 64);
    gemm_kernel<<<grid, 256, 0, stream>>>(A, W, bias, rowscale, C, M, K, Nout, relu);
}

extern "C" void kernel_launch(void* const* d_in, const int* in_sizes, int n_in,
                              void* d_out, int out_size, void* d_ws, size_t ws_size,
                              hipStream_t stream)
{
    const float* x      = (const float*)d_in[0];
    const int*   ei     = (const int*)d_in[1];
    const float* W1     = (const float*)d_in[2];
    const float* b1     = (const float*)d_in[3];
    const float* W2     = (const float*)d_in[4];
    const float* b2     = (const float*)d_in[5];
    const float* W3     = (const float*)d_in[6];
    const float* b3     = (const float*)d_in[7];
    const float* fc1_W  = (const float*)d_in[8];
    const float* fc1_b  = (const float*)d_in[9];
    const float* fc2aW  = (const float*)d_in[10];
    const float* fc2ab  = (const float*)d_in[11];
    const float* gamma  = (const float*)d_in[12];
    const float* beta   = (const float*)d_in[13];
    const float* fc2bW  = (const float*)d_in[14];
    const float* fc2bb  = (const float*)d_in[15];
    float* out = (float*)d_out;

    const int* src = ei;            // edge_index[0]
    const int* dst = ei + N_EDGES;  // edge_index[1]

    char* w = (char*)d_ws;
    float* dinv = (float*)w;      w += (((size_t)N_NODES * 4) + 255) / 256 * 256;
    float* bn_sum   = (float*)w;  w += 128 * 4;
    float* bn_sumsq = (float*)w;  w += 128 * 4;
    float* bn_a     = (float*)w;  w += 128 * 4;
    float* bn_b     = (float*)w;  w += 128 * 4;
    float* bufA = (float*)w;      w += (size_t)N_NODES * H_DIM * 4;
    float* bufB = (float*)w;

    // 1. degrees -> dinv
    hipMemsetAsync(dinv, 0, (size_t)N_NODES * 4, stream);
    deg_kernel<<<(N_EDGES + 255) / 256, 256, 0, stream>>>(dst, dinv, N_EDGES);
    rsqrt_kernel<<<(N_NODES + 255) / 256, 256, 0, stream>>>(dinv, N_NODES);

    // 2. clip(x) -> bufA [N x 100]
    {
        int t4 = N_NODES * F_IN_DIM / 4;
        clip_kernel<<<(t4 + 255) / 256, 256, 0, stream>>>(x, bufA, t4);
    }

    // GCN layer helper sequence, F_in -> F_out
    // conv1: 100 -> 100
    run_gemm(bufA, W1, nullptr, dinv, bufB, N_NODES, F_IN_DIM, F_IN_DIM, 0, stream);
    hipMemsetAsync(bufA, 0, (size_t)N_NODES * F_IN_DIM * 4, stream);
    {
        unsigned total = (unsigned)N_EDGES * (F_IN_DIM / 4);
        scatter_kernel<<<(total + 255) / 256, 256, 0, stream>>>(bufB, src, dst, bufA, N_EDGES, F_IN_DIM);
        int t = N_NODES * (F_IN_DIM / 4);
        selfloop_kernel<<<(t + 255) / 256, 256, 0, stream>>>(bufA, bufB, dinv, b1, t, F_IN_DIM);
    }

    // conv2: 100 -> 100
    run_gemm(bufA, W2, nullptr, dinv, bufB, N_NODES, F_IN_DIM, F_IN_DIM, 0, stream);
    hipMemsetAsync(bufA, 0, (size_t)N_NODES * F_IN_DIM * 4, stream);
    {
        unsigned total = (unsigned)N_EDGES * (F_IN_DIM / 4);
        scatter_kernel<<<(total + 255) / 256, 256, 0, stream>>>(bufB, src, dst, bufA, N_EDGES, F_IN_DIM);
        int t = N_NODES * (F_IN_DIM / 4);
        selfloop_kernel<<<(t + 255) / 256, 256, 0, stream>>>(bufA, bufB, dinv, b2, t, F_IN_DIM);
    }

    // conv3: 100 -> 256
    run_gemm(bufA, W3, nullptr, dinv, bufB, N_NODES, F_IN_DIM, H_DIM, 0, stream);
    hipMemsetAsync(bufA, 0, (size_t)N_NODES * H_DIM * 4, stream);
    {
        unsigned total = (unsigned)N_EDGES * (H_DIM / 4);
        scatter_kernel<<<(total + 255) / 256, 256, 0, stream>>>(bufB, src, dst, bufA, N_EDGES, H_DIM);
        int t = N_NODES * (H_DIM / 4);
        selfloop_kernel<<<(t + 255) / 256, 256, 0, stream>>>(bufA, bufB, dinv, b3, t, H_DIM);
    }

    // fc1: 256 -> 256, relu -> bufB
    run_gemm(bufA, fc1_W, fc1_b, nullptr, bufB, N_NODES, H_DIM, H_DIM, 1, stream);

    // fc2a: 256 -> 128 -> bufA
    run_gemm(bufB, fc2aW, fc2ab, nullptr, bufA, N_NODES, H_DIM, BN_DIM, 0, stream);

    // BN (train mode, batch stats) + relu, in place on bufA
    hipMemsetAsync(bn_sum, 0, 2 * 128 * 4, stream);  // bn_sum and bn_sumsq contiguous
    bn_stats_kernel<<<512, 256, 0, stream>>>(bufA, bn_sum, bn_sumsq, N_NODES);
    bn_finalize_kernel<<<1, 128, 0, stream>>>(bn_sum, bn_sumsq, gamma, beta, bn_a, bn_b, N_NODES);
    {
        int t4 = N_NODES * BN_DIM / 4;
        bn_apply_kernel<<<(t4 + 255) / 256, 256, 0, stream>>>(bufA, bn_a, bn_b, t4);
    }

    // fc2b: 128 -> 19 -> bufB (logits)
    run_gemm(bufA, fc2bW, fc2bb, nullptr, bufB, N_NODES, BN_DIM, N_LABELS, 0, stream);

    // log_softmax -> out
    logsoftmax_kernel<<<(N_NODES + 255) / 256, 256, 0, stream>>>(bufB, out, N_NODES);
}

// Round 2
// 1826.480 us; speedup vs baseline: 6.3374x; 6.3374x over previous
//
#include <hip/hip_runtime.h>

#define N_NODES 100000
#define N_EDGES 1600000
#define F_IN_DIM 100
#define H_DIM 256
#define BN_DIM 128
#define N_LABELS 19
#define BN_EPS 1e-5f

#define SCAN_CHUNK 2048

// ---------------------------------------------------------------- CSR build
__global__ void hist_kernel(const int* __restrict__ dst, int* __restrict__ indeg, int E) {
    int e = blockIdx.x * blockDim.x + threadIdx.x;
    if (e < E) atomicAdd(&indeg[dst[e]], 1);
}

__global__ void scan_partial(const int* __restrict__ in, int* __restrict__ blocksum, int n) {
    __shared__ int ls[256];
    int base = blockIdx.x * SCAN_CHUNK;
    int s = 0;
    for (int i = threadIdx.x; i < SCAN_CHUNK; i += 256) {
        int g = base + i;
        s += (g < n) ? in[g] : 0;
    }
    ls[threadIdx.x] = s;
    __syncthreads();
    for (int off = 128; off > 0; off >>= 1) {
        if (threadIdx.x < off) ls[threadIdx.x] += ls[threadIdx.x + off];
        __syncthreads();
    }
    if (threadIdx.x == 0) blocksum[blockIdx.x] = ls[0];
}

__global__ void scan_blocks(int* __restrict__ blocksum, int nb) {
    if (threadIdx.x == 0 && blockIdx.x == 0) {
        int acc = 0;
        for (int i = 0; i < nb; i++) { int v = blocksum[i]; blocksum[i] = acc; acc += v; }
    }
}

__global__ void scan_final(const int* __restrict__ in, const int* __restrict__ blocksum,
                           int* __restrict__ row_start, int* __restrict__ cursor,
                           int n, int total) {
    __shared__ int ts[256];
    int base = blockIdx.x * SCAN_CHUNK;
    int tid = threadIdx.x;
    int loc[8];
    int s = 0;
    int b0 = base + tid * 8;
    #pragma unroll
    for (int j = 0; j < 8; j++) {
        int g = b0 + j;
        int v = (g < n) ? in[g] : 0;
        loc[j] = s; s += v;
    }
    ts[tid] = s;
    __syncthreads();
    // inclusive Hillis-Steele scan of ts
    for (int off = 1; off < 256; off <<= 1) {
        int v = ts[tid];
        int add = (tid >= off) ? ts[tid - off] : 0;
        __syncthreads();
        ts[tid] = v + add;
        __syncthreads();
    }
    int texc = (tid > 0) ? ts[tid - 1] : 0;
    int boff = blocksum[blockIdx.x];
    #pragma unroll
    for (int j = 0; j < 8; j++) {
        int g = b0 + j;
        if (g < n) { int v = boff + texc + loc[j]; row_start[g] = v; cursor[g] = v; }
    }
    if (blockIdx.x == 0 && tid == 0) row_start[n] = total;
}

__global__ void fill_csr(const int* __restrict__ src, const int* __restrict__ dst,
                         int* __restrict__ cursor, int* __restrict__ src_sorted, int E) {
    int e = blockIdx.x * blockDim.x + threadIdx.x;
    if (e < E) {
        int pos = atomicAdd(&cursor[dst[e]], 1);
        src_sorted[pos] = src[e];
    }
}

__global__ void dinv_kernel(const int* __restrict__ indeg, float* __restrict__ dinv, int n) {
    int i = blockIdx.x * blockDim.x + threadIdx.x;
    if (i < n) dinv[i] = rsqrtf((float)indeg[i] + 1.0f);
}

// ---------------------------------------------------------------- clip
__global__ void clip_kernel(const float* __restrict__ x, float* __restrict__ out, int total4) {
    int i = blockIdx.x * blockDim.x + threadIdx.x;
    if (i >= total4) return;
    float4 v = ((const float4*)x)[i];
    v.x = fminf(fmaxf(v.x, -0.4f), 0.4f);
    v.y = fminf(fmaxf(v.y, -0.4f), 0.4f);
    v.z = fminf(fmaxf(v.z, -0.4f), 0.4f);
    v.w = fminf(fmaxf(v.w, -0.4f), 0.4f);
    ((float4*)out)[i] = v;
}

// ---------------------------------------------------------------- GEMM
// C[M x Nout] = A[M x K] @ W[K x Nout]; optional bias (len Nout),
// optional per-row scale (applied after bias), optional relu.
// 64x64 tile, 256 threads, 4x4 micro-tile, BK=32.
__global__ __launch_bounds__(256) void gemm_kernel(
    const float* __restrict__ A, const float* __restrict__ W,
    const float* __restrict__ bias, const float* __restrict__ rowscale,
    float* __restrict__ C, int M, int K, int Nout, int relu)
{
    __shared__ float As[32][68];
    __shared__ float Bs[32][64];
    int tid = threadIdx.x;
    int tn = tid & 15, tm = tid >> 4;
    int rowBase = blockIdx.y * 64;
    int colBase = blockIdx.x * 64;
    float acc[4][4] = {};

    for (int k0 = 0; k0 < K; k0 += 32) {
        #pragma unroll
        for (int i = 0; i < 8; i++) {
            int lin = tid + i * 256;
            int r = lin >> 5, c = lin & 31;
            int gr = rowBase + r, gc = k0 + c;
            float v = (gr < M && gc < K) ? A[(size_t)gr * K + gc] : 0.f;
            As[c][r] = v;
        }
        #pragma unroll
        for (int i = 0; i < 8; i++) {
            int lin = tid + i * 256;
            int kk = lin >> 6, nn = lin & 63;
            int gk = k0 + kk, gn = colBase + nn;
            float v = (gk < K && gn < Nout) ? W[(size_t)gk * Nout + gn] : 0.f;
            Bs[kk][nn] = v;
        }
        __syncthreads();
        #pragma unroll
        for (int k = 0; k < 32; k++) {
            float a[4], b[4];
            #pragma unroll
            for (int i = 0; i < 4; i++) a[i] = As[k][tm * 4 + i];
            #pragma unroll
            for (int j = 0; j < 4; j++) b[j] = Bs[k][tn * 4 + j];
            #pragma unroll
            for (int i = 0; i < 4; i++)
                #pragma unroll
                for (int j = 0; j < 4; j++)
                    acc[i][j] = fmaf(a[i], b[j], acc[i][j]);
        }
        __syncthreads();
    }

    #pragma unroll
    for (int i = 0; i < 4; i++) {
        int r = rowBase + tm * 4 + i;
        if (r >= M) continue;
        float rs = rowscale ? rowscale[r] : 1.f;
        #pragma unroll
        for (int j = 0; j < 4; j++) {
            int c = colBase + tn * 4 + j;
            if (c >= Nout) continue;
            float v = acc[i][j];
            if (bias) v += bias[c];
            v *= rs;
            if (relu) v = fmaxf(v, 0.f);
            C[(size_t)r * Nout + c] = v;
        }
    }
}

// ---------------------------------------------------------------- gather aggregation
// out[d] = relu(dinv[d] * (sum_{e in in(d)} xws[src[e]] + xws[d]) + bias)
// T lanes per node; each active lane owns one float4 column chunk.
template<int F, int T>
__global__ void gather_kernel(const float* __restrict__ xws,
                              const int* __restrict__ row_start,
                              const int* __restrict__ src_sorted,
                              const float* __restrict__ dinv,
                              const float* __restrict__ bias,
                              float* __restrict__ out, int n)
{
    constexpr int C = F / 4;  // float4 chunks per row
    int group = (blockIdx.x * blockDim.x + threadIdx.x) / T;
    int lane = threadIdx.x % T;
    if (group >= n) return;
    int d = group;
    int e0 = row_start[d], e1 = row_start[d + 1];
    bool active = (lane < C);
    int coff = lane * 4;
    float4 acc = make_float4(0.f, 0.f, 0.f, 0.f);
    for (int e = e0; e < e1; e++) {
        int s = src_sorted[e];
        if (active) {
            float4 v = *(const float4*)(xws + (size_t)s * F + coff);
            acc.x += v.x; acc.y += v.y; acc.z += v.z; acc.w += v.w;
        }
    }
    if (active) {
        float4 xv = *(const float4*)(xws + (size_t)d * F + coff);
        float di = dinv[d];
        float4 o;
        o.x = fmaxf(di * (acc.x + xv.x) + bias[coff + 0], 0.f);
        o.y = fmaxf(di * (acc.y + xv.y) + bias[coff + 1], 0.f);
        o.z = fmaxf(di * (acc.z + xv.z) + bias[coff + 2], 0.f);
        o.w = fmaxf(di * (acc.w + xv.w) + bias[coff + 3], 0.f);
        *(float4*)(out + (size_t)d * F + coff) = o;
    }
}

// ---------------------------------------------------------------- BN
__global__ void bn_stats_kernel(const float* __restrict__ h,
                                float* __restrict__ sum, float* __restrict__ sumsq, int Ntot)
{
    int c = threadIdx.x & 127;
    int rpb = blockDim.x >> 7;
    int r0 = blockIdx.x * rpb + (threadIdx.x >> 7);
    int stride = gridDim.x * rpb;
    float s = 0.f, ss = 0.f;
    for (int r = r0; r < Ntot; r += stride) {
        float v = h[(size_t)r * BN_DIM + c];
        s += v; ss += v * v;
    }
    __shared__ float ls[256], lss[256];
    ls[threadIdx.x] = s; lss[threadIdx.x] = ss;
    __syncthreads();
    if (threadIdx.x < 128) {
        s = ls[threadIdx.x] + ls[threadIdx.x + 128];
        ss = lss[threadIdx.x] + lss[threadIdx.x + 128];
        atomicAdd(&sum[c], s);
        atomicAdd(&sumsq[c], ss);
    }
}

__global__ void bn_finalize_kernel(const float* __restrict__ sum, const float* __restrict__ sumsq,
                                   const float* __restrict__ gamma, const float* __restrict__ beta,
                                   float* __restrict__ a, float* __restrict__ b, int Ntot)
{
    int c = threadIdx.x;
    float inv_n = 1.0f / (float)Ntot;
    float mu = sum[c] * inv_n;
    float var = sumsq[c] * inv_n - mu * mu;
    float ai = gamma[c] * rsqrtf(var + BN_EPS);
    a[c] = ai;
    b[c] = beta[c] - mu * ai;
}

__global__ void bn_apply_kernel(float* __restrict__ h,
                                const float* __restrict__ a, const float* __restrict__ b,
                                int total4)
{
    int i = blockIdx.x * blockDim.x + threadIdx.x;
    if (i >= total4) return;
    int c = (i & 31) << 2;
    float4 v = ((float4*)h)[i];
    v.x = fmaxf(v.x * a[c + 0] + b[c + 0], 0.f);
    v.y = fmaxf(v.y * a[c + 1] + b[c + 1], 0.f);
    v.z = fmaxf(v.z * a[c + 2] + b[c + 2], 0.f);
    v.w = fmaxf(v.w * a[c + 3] + b[c + 3], 0.f);
    ((float4*)h)[i] = v;
}

// ---------------------------------------------------------------- log_softmax
__global__ void logsoftmax_kernel(const float* __restrict__ logits, float* __restrict__ out, int Ntot)
{
    int r = blockIdx.x * blockDim.x + threadIdx.x;
    if (r >= Ntot) return;
    const float* p = logits + (size_t)r * N_LABELS;
    float m = p[0];
    #pragma unroll
    for (int j = 1; j < N_LABELS; j++) m = fmaxf(m, p[j]);
    float s = 0.f;
    #pragma unroll
    for (int j = 0; j < N_LABELS; j++) s += expf(p[j] - m);
    float lse = m + logf(s);
    float* o = out + (size_t)r * N_LABELS;
    #pragma unroll
    for (int j = 0; j < N_LABELS; j++) o[j] = p[j] - lse;
}

// ================================================================ launch
static inline void run_gemm(const float* A, const float* W, const float* bias,
                            const float* rowscale, float* C,
                            int M, int K, int Nout, int relu, hipStream_t stream)
{
    dim3 grid((Nout + 63) / 64, (M + 63) / 64);
    gemm_kernel<<<grid, 256, 0, stream>>>(A, W, bias, rowscale, C, M, K, Nout, relu);
}

extern "C" void kernel_launch(void* const* d_in, const int* in_sizes, int n_in,
                              void* d_out, int out_size, void* d_ws, size_t ws_size,
                              hipStream_t stream)
{
    const float* x      = (const float*)d_in[0];
    const int*   ei     = (const int*)d_in[1];
    const float* W1     = (const float*)d_in[2];
    const float* b1     = (const float*)d_in[3];
    const float* W2     = (const float*)d_in[4];
    const float* b2     = (const float*)d_in[5];
    const float* W3     = (const float*)d_in[6];
    const float* b3     = (const float*)d_in[7];
    const float* fc1_W  = (const float*)d_in[8];
    const float* fc1_b  = (const float*)d_in[9];
    const float* fc2aW  = (const float*)d_in[10];
    const float* fc2ab  = (const float*)d_in[11];
    const float* gamma  = (const float*)d_in[12];
    const float* beta   = (const float*)d_in[13];
    const float* fc2bW  = (const float*)d_in[14];
    const float* fc2bb  = (const float*)d_in[15];
    float* out = (float*)d_out;

    const int* src = ei;
    const int* dst = ei + N_EDGES;

    char* w = (char*)d_ws;
    float* dinv       = (float*)w;  w += ((size_t)N_NODES * 4 + 255) / 256 * 256;
    int*   indeg      = (int*)w;    w += ((size_t)N_NODES * 4 + 255) / 256 * 256;
    int*   row_start  = (int*)w;    w += ((size_t)(N_NODES + 1) * 4 + 255) / 256 * 256;
    int*   cursor     = (int*)w;    w += ((size_t)N_NODES * 4 + 255) / 256 * 256;
    int*   blocksum   = (int*)w;    w += 4096;
    float* bn_sum     = (float*)w;  w += 128 * 4;
    float* bn_sumsq   = (float*)w;  w += 128 * 4;
    float* bn_a       = (float*)w;  w += 128 * 4;
    float* bn_b       = (float*)w;  w += 128 * 4;
    int*   src_sorted = (int*)w;    w += ((size_t)N_EDGES * 4 + 255) / 256 * 256;
    float* bufA       = (float*)w;  w += (size_t)N_NODES * H_DIM * 4;
    float* bufB       = (float*)w;

    const int nScanBlocks = (N_NODES + SCAN_CHUNK - 1) / SCAN_CHUNK;  // 49

    // ---- CSR build + dinv
    hipMemsetAsync(indeg, 0, (size_t)N_NODES * 4, stream);
    hist_kernel<<<(N_EDGES + 255) / 256, 256, 0, stream>>>(dst, indeg, N_EDGES);
    scan_partial<<<nScanBlocks, 256, 0, stream>>>(indeg, blocksum, N_NODES);
    scan_blocks<<<1, 64, 0, stream>>>(blocksum, nScanBlocks);
    scan_final<<<nScanBlocks, 256, 0, stream>>>(indeg, blocksum, row_start, cursor, N_NODES, N_EDGES);
    fill_csr<<<(N_EDGES + 255) / 256, 256, 0, stream>>>(src, dst, cursor, src_sorted, N_EDGES);
    dinv_kernel<<<(N_NODES + 255) / 256, 256, 0, stream>>>(indeg, dinv, N_NODES);

    // ---- clip(x) -> bufA [N x 100]
    {
        int t4 = N_NODES * F_IN_DIM / 4;
        clip_kernel<<<(t4 + 255) / 256, 256, 0, stream>>>(x, bufA, t4);
    }

    // ---- conv1: 100 -> 100
    run_gemm(bufA, W1, nullptr, dinv, bufB, N_NODES, F_IN_DIM, F_IN_DIM, 0, stream);
    gather_kernel<F_IN_DIM, 32><<<(N_NODES * 32 + 255) / 256, 256, 0, stream>>>(
        bufB, row_start, src_sorted, dinv, b1, bufA, N_NODES);

    // ---- conv2: 100 -> 100
    run_gemm(bufA, W2, nullptr, dinv, bufB, N_NODES, F_IN_DIM, F_IN_DIM, 0, stream);
    gather_kernel<F_IN_DIM, 32><<<(N_NODES * 32 + 255) / 256, 256, 0, stream>>>(
        bufB, row_start, src_sorted, dinv, b2, bufA, N_NODES);

    // ---- conv3: 100 -> 256
    run_gemm(bufA, W3, nullptr, dinv, bufB, N_NODES, F_IN_DIM, H_DIM, 0, stream);
    gather_kernel<H_DIM, 64><<<(N_NODES * 64 + 255) / 256, 256, 0, stream>>>(
        bufB, row_start, src_sorted, dinv, b3, bufA, N_NODES);

    // ---- fc1: 256 -> 256, relu -> bufB
    run_gemm(bufA, fc1_W, fc1_b, nullptr, bufB, N_NODES, H_DIM, H_DIM, 1, stream);

    // ---- fc2a: 256 -> 128 -> bufA
    run_gemm(bufB, fc2aW, fc2ab, nullptr, bufA, N_NODES, H_DIM, BN_DIM, 0, stream);

    // ---- BN + relu (in place on bufA)
    hipMemsetAsync(bn_sum, 0, 2 * 128 * 4, stream);
    bn_stats_kernel<<<512, 256, 0, stream>>>(bufA, bn_sum, bn_sumsq, N_NODES);
    bn_finalize_kernel<<<1, 128, 0, stream>>>(bn_sum, bn_sumsq, gamma, beta, bn_a, bn_b, N_NODES);
    {
        int t4 = N_NODES * BN_DIM / 4;
        bn_apply_kernel<<<(t4 + 255) / 256, 256, 0, stream>>>(bufA, bn_a, bn_b, t4);
    }

    // ---- fc2b: 128 -> 19 -> bufB (logits)
    run_gemm(bufA, fc2bW, fc2bb, nullptr, bufB, N_NODES, BN_DIM, N_LABELS, 0, stream);

    // ---- log_softmax -> out
    logsoftmax_kernel<<<(N_NODES + 255) / 256, 256, 0, stream>>>(bufB, out, N_NODES);
}

// Round 3
// 1251.896 us; speedup vs baseline: 9.2462x; 1.4590x over previous
//
#include <hip/hip_runtime.h>
#include <hip/hip_bf16.h>

#define N_NODES 100000
#define N_EDGES 1600000
#define F_IN_DIM 100
#define H_DIM 256
#define BN_DIM 128
#define N_LABELS 19
#define BN_EPS 1e-5f

#define SCAN_CHUNK 2048

typedef __attribute__((ext_vector_type(8))) short bf16x8;   // 4 VGPRs, MFMA A/B frag
typedef __attribute__((ext_vector_type(4))) short s16x4;    // 8B
typedef __attribute__((ext_vector_type(4))) float f32x4;    // MFMA C/D frag

static __device__ inline short f2bf(float f) {
    __hip_bfloat16 h = __float2bfloat16(f);
    return *(short*)&h;
}

// ---------------------------------------------------------------- CSR build
__global__ void hist_kernel(const int* __restrict__ dst, int* __restrict__ indeg, int E) {
    int e = blockIdx.x * blockDim.x + threadIdx.x;
    if (e < E) atomicAdd(&indeg[dst[e]], 1);
}

__global__ void scan_partial(const int* __restrict__ in, int* __restrict__ blocksum, int n) {
    __shared__ int ls[256];
    int base = blockIdx.x * SCAN_CHUNK;
    int s = 0;
    for (int i = threadIdx.x; i < SCAN_CHUNK; i += 256) {
        int g = base + i;
        s += (g < n) ? in[g] : 0;
    }
    ls[threadIdx.x] = s;
    __syncthreads();
    for (int off = 128; off > 0; off >>= 1) {
        if (threadIdx.x < off) ls[threadIdx.x] += ls[threadIdx.x + off];
        __syncthreads();
    }
    if (threadIdx.x == 0) blocksum[blockIdx.x] = ls[0];
}

__global__ void scan_blocks(int* __restrict__ blocksum, int nb) {
    if (threadIdx.x == 0 && blockIdx.x == 0) {
        int acc = 0;
        for (int i = 0; i < nb; i++) { int v = blocksum[i]; blocksum[i] = acc; acc += v; }
    }
}

__global__ void scan_final(const int* __restrict__ in, const int* __restrict__ blocksum,
                           int* __restrict__ row_start, int* __restrict__ cursor,
                           int n, int total) {
    __shared__ int ts[256];
    int base = blockIdx.x * SCAN_CHUNK;
    int tid = threadIdx.x;
    int loc[8];
    int s = 0;
    int b0 = base + tid * 8;
    #pragma unroll
    for (int j = 0; j < 8; j++) {
        int g = b0 + j;
        int v = (g < n) ? in[g] : 0;
        loc[j] = s; s += v;
    }
    ts[tid] = s;
    __syncthreads();
    for (int off = 1; off < 256; off <<= 1) {
        int v = ts[tid];
        int add = (tid >= off) ? ts[tid - off] : 0;
        __syncthreads();
        ts[tid] = v + add;
        __syncthreads();
    }
    int texc = (tid > 0) ? ts[tid - 1] : 0;
    int boff = blocksum[blockIdx.x];
    #pragma unroll
    for (int j = 0; j < 8; j++) {
        int g = b0 + j;
        if (g < n) { int v = boff + texc + loc[j]; row_start[g] = v; cursor[g] = v; }
    }
    if (blockIdx.x == 0 && tid == 0) row_start[n] = total;
}

__global__ void fill_csr(const int* __restrict__ src, const int* __restrict__ dst,
                         int* __restrict__ cursor, int* __restrict__ src_sorted, int E) {
    int e = blockIdx.x * blockDim.x + threadIdx.x;
    if (e < E) {
        int pos = atomicAdd(&cursor[dst[e]], 1);
        src_sorted[pos] = src[e];
    }
}

__global__ void dinv_kernel(const int* __restrict__ indeg, float* __restrict__ dinv, int n) {
    int i = blockIdx.x * blockDim.x + threadIdx.x;
    if (i < n) dinv[i] = rsqrtf((float)indeg[i] + 1.0f);
}

// ---------------------------------------------------------------- weight pack
// Wt[n][k] = bf16(W[k][n]); idx contiguous in k -> coalesced writes.
__global__ void pack_wt(const float* __restrict__ W, short* __restrict__ Wt, int K, int N) {
    int idx = blockIdx.x * blockDim.x + threadIdx.x;
    if (idx >= K * N) return;
    int n = idx / K, k = idx - n * K;
    Wt[idx] = f2bf(W[(size_t)k * N + n]);
}

// ---------------------------------------------------------------- MFMA GEMM
// C[M x Nout] = A[M x K](fp32, bf16-converted in staging) @ Wt^T (Wt is [Nout x K] bf16)
// optional clip of A, bias, rowscale (after bias), relu.
// 128x128 tile, 256 threads (4 waves), each wave 64x64 = 4x4 frags of 16x16x32.
#define BKP 40  // padded LDS row stride in shorts (80B: 16B-aligned, conflict-free frags)
__global__ __launch_bounds__(256) void gemm_mfma(
    const float* __restrict__ A, const short* __restrict__ Wt,
    const float* __restrict__ bias, const float* __restrict__ rowscale,
    float* __restrict__ C, int M, int K, int Nout, int relu, int doclip)
{
    __shared__ __align__(16) short As[128][BKP];
    __shared__ __align__(16) short Bs[128][BKP];

    int tid = threadIdx.x;
    int wid = tid >> 6;
    int lane = tid & 63;
    int quad = lane >> 4;
    int l15 = lane & 15;
    int wave_m = (wid & 1) * 64;
    int wave_n = (wid >> 1) * 64;
    int rowBase = blockIdx.y * 128;
    int colBase = blockIdx.x * 128;

    f32x4 acc[4][4];
    #pragma unroll
    for (int i = 0; i < 4; i++)
        #pragma unroll
        for (int j = 0; j < 4; j++)
            acc[i][j] = (f32x4){0.f, 0.f, 0.f, 0.f};

    for (int k0 = 0; k0 < K; k0 += 32) {
        // ---- stage A: 128 rows x 32 k, fp32 -> bf16
        #pragma unroll
        for (int i = 0; i < 4; i++) {
            int ch = tid + i * 256;          // 1024 float4 chunks
            int r = ch >> 3, c4 = (ch & 7) << 2;
            int gr = rowBase + r, gk = k0 + c4;
            float4 v = make_float4(0.f, 0.f, 0.f, 0.f);
            if (gr < M && gk < K)            // K % 4 == 0 for all layers
                v = *(const float4*)(A + (size_t)gr * K + gk);
            if (doclip) {
                v.x = fminf(fmaxf(v.x, -0.4f), 0.4f);
                v.y = fminf(fmaxf(v.y, -0.4f), 0.4f);
                v.z = fminf(fmaxf(v.z, -0.4f), 0.4f);
                v.w = fminf(fmaxf(v.w, -0.4f), 0.4f);
            }
            s16x4 o = (s16x4){f2bf(v.x), f2bf(v.y), f2bf(v.z), f2bf(v.w)};
            *(s16x4*)(&As[r][c4]) = o;
        }
        // ---- stage B: 128 n x 32 k from Wt[n][k] (already bf16)
        #pragma unroll
        for (int i = 0; i < 4; i++) {
            int ch = tid + i * 256;
            int n = ch >> 3, c4 = (ch & 7) << 2;
            int gn = colBase + n, gk = k0 + c4;
            s16x4 o = (s16x4){0, 0, 0, 0};
            if (gn < Nout && gk < K)
                o = *(const s16x4*)(Wt + (size_t)gn * K + gk);
            *(s16x4*)(&Bs[n][c4]) = o;
        }
        __syncthreads();

        bf16x8 a[4], b[4];
        #pragma unroll
        for (int im = 0; im < 4; im++)
            a[im] = *(const bf16x8*)(&As[wave_m + im * 16 + l15][quad * 8]);
        #pragma unroll
        for (int in = 0; in < 4; in++)
            b[in] = *(const bf16x8*)(&Bs[wave_n + in * 16 + l15][quad * 8]);
        #pragma unroll
        for (int im = 0; im < 4; im++)
            #pragma unroll
            for (int in = 0; in < 4; in++)
                acc[im][in] = __builtin_amdgcn_mfma_f32_16x16x32_bf16(
                    a[im], b[in], acc[im][in], 0, 0, 0);
        __syncthreads();
    }

    // ---- epilogue: C/D layout col=lane&15, row=quad*4+reg
    #pragma unroll
    for (int im = 0; im < 4; im++) {
        #pragma unroll
        for (int reg = 0; reg < 4; reg++) {
            int row = rowBase + wave_m + im * 16 + quad * 4 + reg;
            if (row >= M) continue;
            float rs = rowscale ? rowscale[row] : 1.f;
            #pragma unroll
            for (int in = 0; in < 4; in++) {
                int col = colBase + wave_n + in * 16 + l15;
                if (col >= Nout) continue;
                float v = acc[im][in][reg];
                if (bias) v += bias[col];
                v *= rs;
                if (relu) v = fmaxf(v, 0.f);
                C[(size_t)row * Nout + col] = v;
            }
        }
    }
}

// ---------------------------------------------------------------- fp32 GEMM (fc2b only)
__global__ __launch_bounds__(256) void gemm_kernel(
    const float* __restrict__ A, const float* __restrict__ W,
    const float* __restrict__ bias, const float* __restrict__ rowscale,
    float* __restrict__ C, int M, int K, int Nout, int relu)
{
    __shared__ float Asf[32][68];
    __shared__ float Bsf[32][64];
    int tid = threadIdx.x;
    int tn = tid & 15, tm = tid >> 4;
    int rowBase = blockIdx.y * 64;
    int colBase = blockIdx.x * 64;
    float acc[4][4] = {};

    for (int k0 = 0; k0 < K; k0 += 32) {
        #pragma unroll
        for (int i = 0; i < 8; i++) {
            int lin = tid + i * 256;
            int r = lin >> 5, c = lin & 31;
            int gr = rowBase + r, gc = k0 + c;
            float v = (gr < M && gc < K) ? A[(size_t)gr * K + gc] : 0.f;
            Asf[c][r] = v;
        }
        #pragma unroll
        for (int i = 0; i < 8; i++) {
            int lin = tid + i * 256;
            int kk = lin >> 6, nn = lin & 63;
            int gk = k0 + kk, gn = colBase + nn;
            float v = (gk < K && gn < Nout) ? W[(size_t)gk * Nout + gn] : 0.f;
            Bsf[kk][nn] = v;
        }
        __syncthreads();
        #pragma unroll
        for (int k = 0; k < 32; k++) {
            float a[4], b[4];
            #pragma unroll
            for (int i = 0; i < 4; i++) a[i] = Asf[k][tm * 4 + i];
            #pragma unroll
            for (int j = 0; j < 4; j++) b[j] = Bsf[k][tn * 4 + j];
            #pragma unroll
            for (int i = 0; i < 4; i++)
                #pragma unroll
                for (int j = 0; j < 4; j++)
                    acc[i][j] = fmaf(a[i], b[j], acc[i][j]);
        }
        __syncthreads();
    }

    #pragma unroll
    for (int i = 0; i < 4; i++) {
        int r = rowBase + tm * 4 + i;
        if (r >= M) continue;
        float rs = rowscale ? rowscale[r] : 1.f;
        #pragma unroll
        for (int j = 0; j < 4; j++) {
            int c = colBase + tn * 4 + j;
            if (c >= Nout) continue;
            float v = acc[i][j];
            if (bias) v += bias[c];
            v *= rs;
            if (relu) v = fmaxf(v, 0.f);
            C[(size_t)r * Nout + c] = v;
        }
    }
}

// ---------------------------------------------------------------- gather aggregation
template<int F, int T>
__global__ void gather_kernel(const float* __restrict__ xws,
                              const int* __restrict__ row_start,
                              const int* __restrict__ src_sorted,
                              const float* __restrict__ dinv,
                              const float* __restrict__ bias,
                              float* __restrict__ out, int n)
{
    constexpr int C = F / 4;
    int group = (blockIdx.x * blockDim.x + threadIdx.x) / T;
    int lane = threadIdx.x % T;
    if (group >= n) return;
    int d = group;
    int e0 = row_start[d], e1 = row_start[d + 1];
    bool active = (lane < C);
    int coff = lane * 4;
    float4 acc = make_float4(0.f, 0.f, 0.f, 0.f);
    for (int e = e0; e < e1; e++) {
        int s = src_sorted[e];
        if (active) {
            float4 v = *(const float4*)(xws + (size_t)s * F + coff);
            acc.x += v.x; acc.y += v.y; acc.z += v.z; acc.w += v.w;
        }
    }
    if (active) {
        float4 xv = *(const float4*)(xws + (size_t)d * F + coff);
        float di = dinv[d];
        float4 o;
        o.x = fmaxf(di * (acc.x + xv.x) + bias[coff + 0], 0.f);
        o.y = fmaxf(di * (acc.y + xv.y) + bias[coff + 1], 0.f);
        o.z = fmaxf(di * (acc.z + xv.z) + bias[coff + 2], 0.f);
        o.w = fmaxf(di * (acc.w + xv.w) + bias[coff + 3], 0.f);
        *(float4*)(out + (size_t)d * F + coff) = o;
    }
}

// ---------------------------------------------------------------- BN
__global__ void bn_stats_kernel(const float* __restrict__ h,
                                float* __restrict__ sum, float* __restrict__ sumsq, int Ntot)
{
    int c = threadIdx.x & 127;
    int rpb = blockDim.x >> 7;
    int r0 = blockIdx.x * rpb + (threadIdx.x >> 7);
    int stride = gridDim.x * rpb;
    float s = 0.f, ss = 0.f;
    for (int r = r0; r < Ntot; r += stride) {
        float v = h[(size_t)r * BN_DIM + c];
        s += v; ss += v * v;
    }
    __shared__ float ls[256], lss[256];
    ls[threadIdx.x] = s; lss[threadIdx.x] = ss;
    __syncthreads();
    if (threadIdx.x < 128) {
        s = ls[threadIdx.x] + ls[threadIdx.x + 128];
        ss = lss[threadIdx.x] + lss[threadIdx.x + 128];
        atomicAdd(&sum[c], s);
        atomicAdd(&sumsq[c], ss);
    }
}

__global__ void bn_finalize_kernel(const float* __restrict__ sum, const float* __restrict__ sumsq,
                                   const float* __restrict__ gamma, const float* __restrict__ beta,
                                   float* __restrict__ a, float* __restrict__ b, int Ntot)
{
    int c = threadIdx.x;
    float inv_n = 1.0f / (float)Ntot;
    float mu = sum[c] * inv_n;
    float var = sumsq[c] * inv_n - mu * mu;
    float ai = gamma[c] * rsqrtf(var + BN_EPS);
    a[c] = ai;
    b[c] = beta[c] - mu * ai;
}

__global__ void bn_apply_kernel(float* __restrict__ h,
                                const float* __restrict__ a, const float* __restrict__ b,
                                int total4)
{
    int i = blockIdx.x * blockDim.x + threadIdx.x;
    if (i >= total4) return;
    int c = (i & 31) << 2;
    float4 v = ((float4*)h)[i];
    v.x = fmaxf(v.x * a[c + 0] + b[c + 0], 0.f);
    v.y = fmaxf(v.y * a[c + 1] + b[c + 1], 0.f);
    v.z = fmaxf(v.z * a[c + 2] + b[c + 2], 0.f);
    v.w = fmaxf(v.w * a[c + 3] + b[c + 3], 0.f);
    ((float4*)h)[i] = v;
}

// ---------------------------------------------------------------- log_softmax
__global__ void logsoftmax_kernel(const float* __restrict__ logits, float* __restrict__ out, int Ntot)
{
    int r = blockIdx.x * blockDim.x + threadIdx.x;
    if (r >= Ntot) return;
    const float* p = logits + (size_t)r * N_LABELS;
    float m = p[0];
    #pragma unroll
    for (int j = 1; j < N_LABELS; j++) m = fmaxf(m, p[j]);
    float s = 0.f;
    #pragma unroll
    for (int j = 0; j < N_LABELS; j++) s += expf(p[j] - m);
    float lse = m + logf(s);
    float* o = out + (size_t)r * N_LABELS;
    #pragma unroll
    for (int j = 0; j < N_LABELS; j++) o[j] = p[j] - lse;
}

// ================================================================ launch
static inline void run_gemm_mfma(const float* A, const short* Wt, const float* bias,
                                 const float* rowscale, float* C,
                                 int M, int K, int Nout, int relu, int doclip, hipStream_t stream)
{
    dim3 grid((Nout + 127) / 128, (M + 127) / 128);
    gemm_mfma<<<grid, 256, 0, stream>>>(A, Wt, bias, rowscale, C, M, K, Nout, relu, doclip);
}

extern "C" void kernel_launch(void* const* d_in, const int* in_sizes, int n_in,
                              void* d_out, int out_size, void* d_ws, size_t ws_size,
                              hipStream_t stream)
{
    const float* x      = (const float*)d_in[0];
    const int*   ei     = (const int*)d_in[1];
    const float* W1     = (const float*)d_in[2];
    const float* b1     = (const float*)d_in[3];
    const float* W2     = (const float*)d_in[4];
    const float* b2     = (const float*)d_in[5];
    const float* W3     = (const float*)d_in[6];
    const float* b3     = (const float*)d_in[7];
    const float* fc1_W  = (const float*)d_in[8];
    const float* fc1_b  = (const float*)d_in[9];
    const float* fc2aW  = (const float*)d_in[10];
    const float* fc2ab  = (const float*)d_in[11];
    const float* gamma  = (const float*)d_in[12];
    const float* beta   = (const float*)d_in[13];
    const float* fc2bW  = (const float*)d_in[14];
    const float* fc2bb  = (const float*)d_in[15];
    float* out = (float*)d_out;

    const int* src = ei;
    const int* dst = ei + N_EDGES;

    char* w = (char*)d_ws;
    float* dinv       = (float*)w;  w += ((size_t)N_NODES * 4 + 255) / 256 * 256;
    int*   indeg      = (int*)w;    w += ((size_t)N_NODES * 4 + 255) / 256 * 256;
    int*   row_start  = (int*)w;    w += ((size_t)(N_NODES + 1) * 4 + 255) / 256 * 256;
    int*   cursor     = (int*)w;    w += ((size_t)N_NODES * 4 + 255) / 256 * 256;
    int*   blocksum   = (int*)w;    w += 4096;
    float* bn_sum     = (float*)w;  w += 128 * 4;
    float* bn_sumsq   = (float*)w;  w += 128 * 4;
    float* bn_a       = (float*)w;  w += 128 * 4;
    float* bn_b       = (float*)w;  w += 128 * 4;
    short* Wt1        = (short*)w;  w += ((size_t)F_IN_DIM * F_IN_DIM * 2 + 255) / 256 * 256;
    short* Wt2        = (short*)w;  w += ((size_t)F_IN_DIM * F_IN_DIM * 2 + 255) / 256 * 256;
    short* Wt3        = (short*)w;  w += ((size_t)H_DIM * F_IN_DIM * 2 + 255) / 256 * 256;
    short* Wtf1       = (short*)w;  w += ((size_t)H_DIM * H_DIM * 2 + 255) / 256 * 256;
    short* Wtf2a      = (short*)w;  w += ((size_t)BN_DIM * H_DIM * 2 + 255) / 256 * 256;
    int*   src_sorted = (int*)w;    w += ((size_t)N_EDGES * 4 + 255) / 256 * 256;
    float* bufA       = (float*)w;  w += (size_t)N_NODES * H_DIM * 4;
    float* bufB       = (float*)w;

    const int nScanBlocks = (N_NODES + SCAN_CHUNK - 1) / SCAN_CHUNK;  // 49

    // ---- CSR build + dinv
    hipMemsetAsync(indeg, 0, (size_t)N_NODES * 4, stream);
    hist_kernel<<<(N_EDGES + 255) / 256, 256, 0, stream>>>(dst, indeg, N_EDGES);
    scan_partial<<<nScanBlocks, 256, 0, stream>>>(indeg, blocksum, N_NODES);
    scan_blocks<<<1, 64, 0, stream>>>(blocksum, nScanBlocks);
    scan_final<<<nScanBlocks, 256, 0, stream>>>(indeg, blocksum, row_start, cursor, N_NODES, N_EDGES);
    fill_csr<<<(N_EDGES + 255) / 256, 256, 0, stream>>>(src, dst, cursor, src_sorted, N_EDGES);
    dinv_kernel<<<(N_NODES + 255) / 256, 256, 0, stream>>>(indeg, dinv, N_NODES);

    // ---- pack weights (transpose + bf16)
    pack_wt<<<(F_IN_DIM * F_IN_DIM + 255) / 256, 256, 0, stream>>>(W1, Wt1, F_IN_DIM, F_IN_DIM);
    pack_wt<<<(F_IN_DIM * F_IN_DIM + 255) / 256, 256, 0, stream>>>(W2, Wt2, F_IN_DIM, F_IN_DIM);
    pack_wt<<<(F_IN_DIM * H_DIM + 255) / 256, 256, 0, stream>>>(W3, Wt3, F_IN_DIM, H_DIM);
    pack_wt<<<(H_DIM * H_DIM + 255) / 256, 256, 0, stream>>>(fc1_W, Wtf1, H_DIM, H_DIM);
    pack_wt<<<(H_DIM * BN_DIM + 255) / 256, 256, 0, stream>>>(fc2aW, Wtf2a, H_DIM, BN_DIM);

    // ---- conv1: clip(x) @ W1, rowscale dinv (clip fused into staging)
    run_gemm_mfma(x, Wt1, nullptr, dinv, bufB, N_NODES, F_IN_DIM, F_IN_DIM, 0, 1, stream);
    gather_kernel<F_IN_DIM, 32><<<(N_NODES * 32 + 255) / 256, 256, 0, stream>>>(
        bufB, row_start, src_sorted, dinv, b1, bufA, N_NODES);

    // ---- conv2: 100 -> 100
    run_gemm_mfma(bufA, Wt2, nullptr, dinv, bufB, N_NODES, F_IN_DIM, F_IN_DIM, 0, 0, stream);
    gather_kernel<F_IN_DIM, 32><<<(N_NODES * 32 + 255) / 256, 256, 0, stream>>>(
        bufB, row_start, src_sorted, dinv, b2, bufA, N_NODES);

    // ---- conv3: 100 -> 256
    run_gemm_mfma(bufA, Wt3, nullptr, dinv, bufB, N_NODES, F_IN_DIM, H_DIM, 0, 0, stream);
    gather_kernel<H_DIM, 64><<<(N_NODES * 64 + 255) / 256, 256, 0, stream>>>(
        bufB, row_start, src_sorted, dinv, b3, bufA, N_NODES);

    // ---- fc1: 256 -> 256, relu -> bufB
    run_gemm_mfma(bufA, Wtf1, fc1_b, nullptr, bufB, N_NODES, H_DIM, H_DIM, 1, 0, stream);

    // ---- fc2a: 256 -> 128 -> bufA
    run_gemm_mfma(bufB, Wtf2a, fc2ab, nullptr, bufA, N_NODES, H_DIM, BN_DIM, 0, 0, stream);

    // ---- BN + relu (in place on bufA)
    hipMemsetAsync(bn_sum, 0, 2 * 128 * 4, stream);
    bn_stats_kernel<<<512, 256, 0, stream>>>(bufA, bn_sum, bn_sumsq, N_NODES);
    bn_finalize_kernel<<<1, 128, 0, stream>>>(bn_sum, bn_sumsq, gamma, beta, bn_a, bn_b, N_NODES);
    {
        int t4 = N_NODES * BN_DIM / 4;
        bn_apply_kernel<<<(t4 + 255) / 256, 256, 0, stream>>>(bufA, bn_a, bn_b, t4);
    }

    // ---- fc2b: 128 -> 19 (fp32, skinny) -> bufB (logits)
    {
        dim3 grid((N_LABELS + 63) / 64, (N_NODES + 63) / 64);
        gemm_kernel<<<grid, 256, 0, stream>>>(bufA, fc2bW, fc2bb, nullptr, bufB,
                                              N_NODES, BN_DIM, N_LABELS, 0);
    }

    // ---- log_softmax -> out
    logsoftmax_kernel<<<(N_NODES + 255) / 256, 256, 0, stream>>>(bufB, out, N_NODES);
}

// Round 4
// 988.775 us; speedup vs baseline: 11.7066x; 1.2661x over previous
//
#include <hip/hip_runtime.h>
#include <hip/hip_bf16.h>

#define N_NODES 100000
#define N_EDGES 1600000
#define F_IN_DIM 100
#define F_IN_PAD 104     // padded bf16 row stride (13 x 16B chunks)
#define H_DIM 256
#define BN_DIM 128
#define N_LABELS 19
#define BN_EPS 1e-5f

#define SCAN_CHUNK 2048

typedef __attribute__((ext_vector_type(8))) short bf16x8;   // 4 VGPRs, MFMA A/B frag / 16B
typedef __attribute__((ext_vector_type(4))) short s16x4;    // 8B
typedef __attribute__((ext_vector_type(4))) float f32x4;    // MFMA C/D frag

static __device__ inline short f2bf(float f) {
    __hip_bfloat16 h = __float2bfloat16(f);
    return *(short*)&h;
}
static __device__ inline float bf2f(short s) {
    unsigned u = ((unsigned)(unsigned short)s) << 16;
    return __builtin_bit_cast(float, u);
}

// ---------------------------------------------------------------- CSR build
__global__ void hist_kernel(const int* __restrict__ dst, int* __restrict__ indeg, int E) {
    int e = blockIdx.x * blockDim.x + threadIdx.x;
    if (e < E) atomicAdd(&indeg[dst[e]], 1);
}

__global__ void scan_partial(const int* __restrict__ in, int* __restrict__ blocksum, int n) {
    __shared__ int ls[256];
    int base = blockIdx.x * SCAN_CHUNK;
    int s = 0;
    for (int i = threadIdx.x; i < SCAN_CHUNK; i += 256) {
        int g = base + i;
        s += (g < n) ? in[g] : 0;
    }
    ls[threadIdx.x] = s;
    __syncthreads();
    for (int off = 128; off > 0; off >>= 1) {
        if (threadIdx.x < off) ls[threadIdx.x] += ls[threadIdx.x + off];
        __syncthreads();
    }
    if (threadIdx.x == 0) blocksum[blockIdx.x] = ls[0];
}

__global__ void scan_blocks(int* __restrict__ blocksum, int nb) {
    if (threadIdx.x == 0 && blockIdx.x == 0) {
        int acc = 0;
        for (int i = 0; i < nb; i++) { int v = blocksum[i]; blocksum[i] = acc; acc += v; }
    }
}

__global__ void scan_final(const int* __restrict__ in, const int* __restrict__ blocksum,
                           int* __restrict__ row_start, int* __restrict__ cursor,
                           int n, int total) {
    __shared__ int ts[256];
    int base = blockIdx.x * SCAN_CHUNK;
    int tid = threadIdx.x;
    int loc[8];
    int s = 0;
    int b0 = base + tid * 8;
    #pragma unroll
    for (int j = 0; j < 8; j++) {
        int g = b0 + j;
        int v = (g < n) ? in[g] : 0;
        loc[j] = s; s += v;
    }
    ts[tid] = s;
    __syncthreads();
    for (int off = 1; off < 256; off <<= 1) {
        int v = ts[tid];
        int add = (tid >= off) ? ts[tid - off] : 0;
        __syncthreads();
        ts[tid] = v + add;
        __syncthreads();
    }
    int texc = (tid > 0) ? ts[tid - 1] : 0;
    int boff = blocksum[blockIdx.x];
    #pragma unroll
    for (int j = 0; j < 8; j++) {
        int g = b0 + j;
        if (g < n) { int v = boff + texc + loc[j]; row_start[g] = v; cursor[g] = v; }
    }
    if (blockIdx.x == 0 && tid == 0) row_start[n] = total;
}

__global__ void fill_csr(const int* __restrict__ src, const int* __restrict__ dst,
                         int* __restrict__ cursor, int* __restrict__ src_sorted, int E) {
    int e = blockIdx.x * blockDim.x + threadIdx.x;
    if (e < E) {
        int pos = atomicAdd(&cursor[dst[e]], 1);
        src_sorted[pos] = src[e];
    }
}

__global__ void dinv_kernel(const int* __restrict__ indeg, float* __restrict__ dinv, int n) {
    int i = blockIdx.x * blockDim.x + threadIdx.x;
    if (i < n) dinv[i] = rsqrtf((float)indeg[i] + 1.0f);
}

// ---------------------------------------------------------------- weight pack
// Wt[n][kp] = bf16(W[k][n]) for k<K else 0; row stride Kp (zero-padded).
__global__ void pack_wt(const float* __restrict__ W, short* __restrict__ Wt,
                        int K, int N, int Kp) {
    int idx = blockIdx.x * blockDim.x + threadIdx.x;
    if (idx >= N * Kp) return;
    int n = idx / Kp, k = idx - n * Kp;
    Wt[idx] = (k < K) ? f2bf(W[(size_t)k * N + n]) : (short)0;
}

// ---------------------------------------------------------------- MFMA GEMM
// C[M x Nout] = A[M x K] @ Wt^T  (Wt is [Nout x Kp] bf16, zero-padded)
// A is fp32 (ABF16=0, optional clip) or bf16 (ABF16=1) with row stride strideA.
// Output bf16 (OBF16=1, zeros written in pad cols [Nout,strideC)) or fp32.
// 128x128 tile, 256 threads (4 waves), each wave 64x64 = 4x4 frags of 16x16x32.
#define BKP 40  // padded LDS row stride in shorts (80B: 16B-aligned, conflict-free)
template<int ABF16, int OBF16>
__global__ __launch_bounds__(256) void gemm_mfma(
    const void* __restrict__ Av, const short* __restrict__ Wt,
    const float* __restrict__ bias, const float* __restrict__ rowscale,
    void* __restrict__ Cv, int M, int K, int Kp, int Nout,
    int strideA, int strideC, int relu, int doclip)
{
    __shared__ __align__(16) short As[128][BKP];
    __shared__ __align__(16) short Bs[128][BKP];

    int tid = threadIdx.x;
    int wid = tid >> 6;
    int lane = tid & 63;
    int quad = lane >> 4;
    int l15 = lane & 15;
    int wave_m = (wid & 1) * 64;
    int wave_n = (wid >> 1) * 64;
    int rowBase = blockIdx.y * 128;
    int colBase = blockIdx.x * 128;

    f32x4 acc[4][4];
    #pragma unroll
    for (int i = 0; i < 4; i++)
        #pragma unroll
        for (int j = 0; j < 4; j++)
            acc[i][j] = (f32x4){0.f, 0.f, 0.f, 0.f};

    for (int k0 = 0; k0 < K; k0 += 32) {
        // ---- stage A: 128 rows x 32 k
        if (ABF16) {
            const short* A = (const short*)Av;
            #pragma unroll
            for (int i = 0; i < 2; i++) {
                int ch = tid + i * 256;            // 512 chunks of 8 shorts
                int r = ch >> 2, c8 = (ch & 3) << 3;
                int gr = rowBase + r, gk = k0 + c8;
                bf16x8 o = (bf16x8){0,0,0,0,0,0,0,0};
                if (gr < M && gk < strideA)        // strideA % 8 == 0
                    o = *(const bf16x8*)(A + (size_t)gr * strideA + gk);
                *(bf16x8*)(&As[r][c8]) = o;
            }
        } else {
            const float* A = (const float*)Av;
            #pragma unroll
            for (int i = 0; i < 4; i++) {
                int ch = tid + i * 256;            // 1024 float4 chunks
                int r = ch >> 3, c4 = (ch & 7) << 2;
                int gr = rowBase + r, gk = k0 + c4;
                float4 v = make_float4(0.f, 0.f, 0.f, 0.f);
                if (gr < M && gk < K)              // K % 4 == 0
                    v = *(const float4*)(A + (size_t)gr * strideA + gk);
                if (doclip) {
                    v.x = fminf(fmaxf(v.x, -0.4f), 0.4f);
                    v.y = fminf(fmaxf(v.y, -0.4f), 0.4f);
                    v.z = fminf(fmaxf(v.z, -0.4f), 0.4f);
                    v.w = fminf(fmaxf(v.w, -0.4f), 0.4f);
                }
                s16x4 o = (s16x4){f2bf(v.x), f2bf(v.y), f2bf(v.z), f2bf(v.w)};
                *(s16x4*)(&As[r][c4]) = o;
            }
        }
        // ---- stage B: 128 n x 32 k from Wt[n][Kp]
        #pragma unroll
        for (int i = 0; i < 2; i++) {
            int ch = tid + i * 256;
            int n = ch >> 2, c8 = (ch & 3) << 3;
            int gn = colBase + n, gk = k0 + c8;
            bf16x8 o = (bf16x8){0,0,0,0,0,0,0,0};
            if (gn < Nout && gk < Kp)
                o = *(const bf16x8*)(Wt + (size_t)gn * Kp + gk);
            *(bf16x8*)(&Bs[n][c8]) = o;
        }
        __syncthreads();

        bf16x8 a[4], b[4];
        #pragma unroll
        for (int im = 0; im < 4; im++)
            a[im] = *(const bf16x8*)(&As[wave_m + im * 16 + l15][quad * 8]);
        #pragma unroll
        for (int in = 0; in < 4; in++)
            b[in] = *(const bf16x8*)(&Bs[wave_n + in * 16 + l15][quad * 8]);
        #pragma unroll
        for (int im = 0; im < 4; im++)
            #pragma unroll
            for (int in = 0; in < 4; in++)
                acc[im][in] = __builtin_amdgcn_mfma_f32_16x16x32_bf16(
                    a[im], b[in], acc[im][in], 0, 0, 0);
        __syncthreads();
    }

    // ---- epilogue: C/D layout col=lane&15, row=quad*4+reg
    #pragma unroll
    for (int im = 0; im < 4; im++) {
        #pragma unroll
        for (int reg = 0; reg < 4; reg++) {
            int row = rowBase + wave_m + im * 16 + quad * 4 + reg;
            if (row >= M) continue;
            float rs = rowscale ? rowscale[row] : 1.f;
            #pragma unroll
            for (int in = 0; in < 4; in++) {
                int col = colBase + wave_n + in * 16 + l15;
                float v = 0.f;
                if (col < Nout) {
                    v = acc[im][in][reg];
                    if (bias) v += bias[col];
                    v *= rs;
                    if (relu) v = fmaxf(v, 0.f);
                }
                if (OBF16) {
                    if (col < strideC)
                        ((short*)Cv)[(size_t)row * strideC + col] = f2bf(v);
                } else {
                    if (col < Nout)
                        ((float*)Cv)[(size_t)row * strideC + col] = v;
                }
            }
        }
    }
}

// ---------------------------------------------------------------- fp32 GEMM (fc2b only)
__global__ __launch_bounds__(256) void gemm_kernel(
    const float* __restrict__ A, const float* __restrict__ W,
    const float* __restrict__ bias, float* __restrict__ C,
    int M, int K, int Nout)
{
    __shared__ float Asf[32][68];
    __shared__ float Bsf[32][64];
    int tid = threadIdx.x;
    int tn = tid & 15, tm = tid >> 4;
    int rowBase = blockIdx.y * 64;
    int colBase = blockIdx.x * 64;
    float acc[4][4] = {};

    for (int k0 = 0; k0 < K; k0 += 32) {
        #pragma unroll
        for (int i = 0; i < 8; i++) {
            int lin = tid + i * 256;
            int r = lin >> 5, c = lin & 31;
            int gr = rowBase + r, gc = k0 + c;
            float v = (gr < M && gc < K) ? A[(size_t)gr * K + gc] : 0.f;
            Asf[c][r] = v;
        }
        #pragma unroll
        for (int i = 0; i < 8; i++) {
            int lin = tid + i * 256;
            int kk = lin >> 6, nn = lin & 63;
            int gk = k0 + kk, gn = colBase + nn;
            float v = (gk < K && gn < Nout) ? W[(size_t)gk * Nout + gn] : 0.f;
            Bsf[kk][nn] = v;
        }
        __syncthreads();
        #pragma unroll
        for (int k = 0; k < 32; k++) {
            float a[4], b[4];
            #pragma unroll
            for (int i = 0; i < 4; i++) a[i] = Asf[k][tm * 4 + i];
            #pragma unroll
            for (int j = 0; j < 4; j++) b[j] = Bsf[k][tn * 4 + j];
            #pragma unroll
            for (int i = 0; i < 4; i++)
                #pragma unroll
                for (int j = 0; j < 4; j++)
                    acc[i][j] = fmaf(a[i], b[j], acc[i][j]);
        }
        __syncthreads();
    }

    #pragma unroll
    for (int i = 0; i < 4; i++) {
        int r = rowBase + tm * 4 + i;
        if (r >= M) continue;
        #pragma unroll
        for (int j = 0; j < 4; j++) {
            int c = colBase + tn * 4 + j;
            if (c >= Nout) continue;
            C[(size_t)r * Nout + c] = acc[i][j] + bias[c];
        }
    }
}

// ---------------------------------------------------------------- gather aggregation (bf16)
// out[d][c] = relu(dinv[d] * (sum_{e in in(d)} xws[src[e]][c] + xws[d][c]) + bias[c])
// bf16 in/out, fp32 accumulate. T lanes per node, 16B (8-col) chunk per lane.
template<int F, int STRIDE, int T>
__global__ void gather_kernel(const short* __restrict__ xws,
                              const int* __restrict__ row_start,
                              const int* __restrict__ src_sorted,
                              const float* __restrict__ dinv,
                              const float* __restrict__ bias,
                              short* __restrict__ out, int n)
{
    constexpr int CHUNKS = STRIDE / 8;
    int group = (blockIdx.x * blockDim.x + threadIdx.x) / T;
    int lane = threadIdx.x % T;
    if (group >= n) return;
    int d = group;
    int e0 = row_start[d], e1 = row_start[d + 1];
    bool active = (lane < CHUNKS);
    int coff = lane * 8;
    float acc[8] = {};
    for (int e = e0; e < e1; e++) {
        int s = src_sorted[e];
        if (active) {
            bf16x8 v = *(const bf16x8*)(xws + (size_t)s * STRIDE + coff);
            #pragma unroll
            for (int j = 0; j < 8; j++) acc[j] += bf2f(v[j]);
        }
    }
    if (active) {
        bf16x8 xv = *(const bf16x8*)(xws + (size_t)d * STRIDE + coff);
        float di = dinv[d];
        bf16x8 o;
        #pragma unroll
        for (int j = 0; j < 8; j++) {
            int col = coff + j;
            float v = 0.f;
            if (col < F)
                v = fmaxf(di * (acc[j] + bf2f(xv[j])) + bias[col], 0.f);
            o[j] = f2bf(v);
        }
        *(bf16x8*)(out + (size_t)d * STRIDE + coff) = o;
    }
}

// ---------------------------------------------------------------- BN
__global__ void bn_stats_kernel(const float* __restrict__ h,
                                float* __restrict__ sum, float* __restrict__ sumsq, int Ntot)
{
    int c = threadIdx.x & 127;
    int rpb = blockDim.x >> 7;
    int r0 = blockIdx.x * rpb + (threadIdx.x >> 7);
    int stride = gridDim.x * rpb;
    float s = 0.f, ss = 0.f;
    for (int r = r0; r < Ntot; r += stride) {
        float v = h[(size_t)r * BN_DIM + c];
        s += v; ss += v * v;
    }
    __shared__ float ls[256], lss[256];
    ls[threadIdx.x] = s; lss[threadIdx.x] = ss;
    __syncthreads();
    if (threadIdx.x < 128) {
        s = ls[threadIdx.x] + ls[threadIdx.x + 128];
        ss = lss[threadIdx.x] + lss[threadIdx.x + 128];
        atomicAdd(&sum[c], s);
        atomicAdd(&sumsq[c], ss);
    }
}

__global__ void bn_finalize_kernel(const float* __restrict__ sum, const float* __restrict__ sumsq,
                                   const float* __restrict__ gamma, const float* __restrict__ beta,
                                   float* __restrict__ a, float* __restrict__ b, int Ntot)
{
    int c = threadIdx.x;
    float inv_n = 1.0f / (float)Ntot;
    float mu = sum[c] * inv_n;
    float var = sumsq[c] * inv_n - mu * mu;
    float ai = gamma[c] * rsqrtf(var + BN_EPS);
    a[c] = ai;
    b[c] = beta[c] - mu * ai;
}

__global__ void bn_apply_kernel(float* __restrict__ h,
                                const float* __restrict__ a, const float* __restrict__ b,
                                int total4)
{
    int i = blockIdx.x * blockDim.x + threadIdx.x;
    if (i >= total4) return;
    int c = (i & 31) << 2;
    float4 v = ((float4*)h)[i];
    v.x = fmaxf(v.x * a[c + 0] + b[c + 0], 0.f);
    v.y = fmaxf(v.y * a[c + 1] + b[c + 1], 0.f);
    v.z = fmaxf(v.z * a[c + 2] + b[c + 2], 0.f);
    v.w = fmaxf(v.w * a[c + 3] + b[c + 3], 0.f);
    ((float4*)h)[i] = v;
}

// ---------------------------------------------------------------- log_softmax
__global__ void logsoftmax_kernel(const float* __restrict__ logits, float* __restrict__ out, int Ntot)
{
    int r = blockIdx.x * blockDim.x + threadIdx.x;
    if (r >= Ntot) return;
    const float* p = logits + (size_t)r * N_LABELS;
    float m = p[0];
    #pragma unroll
    for (int j = 1; j < N_LABELS; j++) m = fmaxf(m, p[j]);
    float s = 0.f;
    #pragma unroll
    for (int j = 0; j < N_LABELS; j++) s += expf(p[j] - m);
    float lse = m + logf(s);
    float* o = out + (size_t)r * N_LABELS;
    #pragma unroll
    for (int j = 0; j < N_LABELS; j++) o[j] = p[j] - lse;
}

// ================================================================ launch
extern "C" void kernel_launch(void* const* d_in, const int* in_sizes, int n_in,
                              void* d_out, int out_size, void* d_ws, size_t ws_size,
                              hipStream_t stream)
{
    const float* x      = (const float*)d_in[0];
    const int*   ei     = (const int*)d_in[1];
    const float* W1     = (const float*)d_in[2];
    const float* b1     = (const float*)d_in[3];
    const float* W2     = (const float*)d_in[4];
    const float* b2     = (const float*)d_in[5];
    const float* W3     = (const float*)d_in[6];
    const float* b3     = (const float*)d_in[7];
    const float* fc1_W  = (const float*)d_in[8];
    const float* fc1_b  = (const float*)d_in[9];
    const float* fc2aW  = (const float*)d_in[10];
    const float* fc2ab  = (const float*)d_in[11];
    const float* gamma  = (const float*)d_in[12];
    const float* beta   = (const float*)d_in[13];
    const float* fc2bW  = (const float*)d_in[14];
    const float* fc2bb  = (const float*)d_in[15];
    float* out = (float*)d_out;

    const int* src = ei;
    const int* dst = ei + N_EDGES;

    char* w = (char*)d_ws;
    float* dinv       = (float*)w;  w += ((size_t)N_NODES * 4 + 255) / 256 * 256;
    int*   indeg      = (int*)w;    w += ((size_t)N_NODES * 4 + 255) / 256 * 256;
    int*   row_start  = (int*)w;    w += ((size_t)(N_NODES + 1) * 4 + 255) / 256 * 256;
    int*   cursor     = (int*)w;    w += ((size_t)N_NODES * 4 + 255) / 256 * 256;
    int*   blocksum   = (int*)w;    w += 4096;
    float* bn_sum     = (float*)w;  w += 128 * 4;
    float* bn_sumsq   = (float*)w;  w += 128 * 4;
    float* bn_a       = (float*)w;  w += 128 * 4;
    float* bn_b       = (float*)w;  w += 128 * 4;
    short* Wt1        = (short*)w;  w += ((size_t)F_IN_DIM * F_IN_PAD * 2 + 255) / 256 * 256;
    short* Wt2        = (short*)w;  w += ((size_t)F_IN_DIM * F_IN_PAD * 2 + 255) / 256 * 256;
    short* Wt3        = (short*)w;  w += ((size_t)H_DIM * F_IN_PAD * 2 + 255) / 256 * 256;
    short* Wtf1       = (short*)w;  w += ((size_t)H_DIM * H_DIM * 2 + 255) / 256 * 256;
    short* Wtf2a      = (short*)w;  w += ((size_t)BN_DIM * H_DIM * 2 + 255) / 256 * 256;
    int*   src_sorted = (int*)w;    w += ((size_t)N_EDGES * 4 + 255) / 256 * 256;
    short* xws100     = (short*)w;  w += ((size_t)N_NODES * F_IN_PAD * 2 + 255) / 256 * 256;
    short* agg100     = (short*)w;  w += ((size_t)N_NODES * F_IN_PAD * 2 + 255) / 256 * 256;
    short* big1       = (short*)w;  w += ((size_t)N_NODES * H_DIM * 2 + 255) / 256 * 256;
    short* big2       = (short*)w;  w += ((size_t)N_NODES * H_DIM * 2 + 255) / 256 * 256;
    float* fc2a_out   = (float*)w;  w += ((size_t)N_NODES * BN_DIM * 4 + 255) / 256 * 256;
    float* logits     = (float*)w;

    const int nScanBlocks = (N_NODES + SCAN_CHUNK - 1) / SCAN_CHUNK;  // 49

    // ---- CSR build + dinv
    hipMemsetAsync(indeg, 0, (size_t)N_NODES * 4, stream);
    hist_kernel<<<(N_EDGES + 255) / 256, 256, 0, stream>>>(dst, indeg, N_EDGES);
    scan_partial<<<nScanBlocks, 256, 0, stream>>>(indeg, blocksum, N_NODES);
    scan_blocks<<<1, 64, 0, stream>>>(blocksum, nScanBlocks);
    scan_final<<<nScanBlocks, 256, 0, stream>>>(indeg, blocksum, row_start, cursor, N_NODES, N_EDGES);
    fill_csr<<<(N_EDGES + 255) / 256, 256, 0, stream>>>(src, dst, cursor, src_sorted, N_EDGES);
    dinv_kernel<<<(N_NODES + 255) / 256, 256, 0, stream>>>(indeg, dinv, N_NODES);

    // ---- pack weights (transpose + bf16 + zero-pad K)
    pack_wt<<<(F_IN_DIM * F_IN_PAD + 255) / 256, 256, 0, stream>>>(W1, Wt1, F_IN_DIM, F_IN_DIM, F_IN_PAD);
    pack_wt<<<(F_IN_DIM * F_IN_PAD + 255) / 256, 256, 0, stream>>>(W2, Wt2, F_IN_DIM, F_IN_DIM, F_IN_PAD);
    pack_wt<<<(H_DIM * F_IN_PAD + 255) / 256, 256, 0, stream>>>(W3, Wt3, F_IN_DIM, H_DIM, F_IN_PAD);
    pack_wt<<<(H_DIM * H_DIM + 255) / 256, 256, 0, stream>>>(fc1_W, Wtf1, H_DIM, H_DIM, H_DIM);
    pack_wt<<<(BN_DIM * H_DIM + 255) / 256, 256, 0, stream>>>(fc2aW, Wtf2a, H_DIM, BN_DIM, H_DIM);

    dim3 g100(1, (N_NODES + 127) / 128);
    dim3 g256(2, (N_NODES + 127) / 128);

    // ---- conv1: clip(x) @ W1, rowscale dinv -> xws100 (bf16, stride 104)
    gemm_mfma<0, 1><<<g100, 256, 0, stream>>>(x, Wt1, nullptr, dinv, xws100,
        N_NODES, F_IN_DIM, F_IN_PAD, F_IN_DIM, F_IN_DIM, F_IN_PAD, 0, 1);
    gather_kernel<F_IN_DIM, F_IN_PAD, 16><<<(N_NODES * 16 + 255) / 256, 256, 0, stream>>>(
        xws100, row_start, src_sorted, dinv, b1, agg100, N_NODES);

    // ---- conv2: 100 -> 100
    gemm_mfma<1, 1><<<g100, 256, 0, stream>>>(agg100, Wt2, nullptr, dinv, xws100,
        N_NODES, F_IN_DIM, F_IN_PAD, F_IN_DIM, F_IN_PAD, F_IN_PAD, 0, 0);
    gather_kernel<F_IN_DIM, F_IN_PAD, 16><<<(N_NODES * 16 + 255) / 256, 256, 0, stream>>>(
        xws100, row_start, src_sorted, dinv, b2, agg100, N_NODES);

    // ---- conv3: 100 -> 256
    gemm_mfma<1, 1><<<g256, 256, 0, stream>>>(agg100, Wt3, nullptr, dinv, big1,
        N_NODES, F_IN_DIM, F_IN_PAD, H_DIM, F_IN_PAD, H_DIM, 0, 0);
    gather_kernel<H_DIM, H_DIM, 32><<<(N_NODES * 32 + 255) / 256, 256, 0, stream>>>(
        big1, row_start, src_sorted, dinv, b3, big2, N_NODES);

    // ---- fc1: 256 -> 256, relu -> big1
    gemm_mfma<1, 1><<<g256, 256, 0, stream>>>(big2, Wtf1, fc1_b, nullptr, big1,
        N_NODES, H_DIM, H_DIM, H_DIM, H_DIM, H_DIM, 1, 0);

    // ---- fc2a: 256 -> 128 -> fc2a_out (fp32)
    gemm_mfma<1, 0><<<g100, 256, 0, stream>>>(big1, Wtf2a, fc2ab, nullptr, fc2a_out,
        N_NODES, H_DIM, H_DIM, BN_DIM, H_DIM, BN_DIM, 0, 0);

    // ---- BN + relu (in place on fc2a_out)
    hipMemsetAsync(bn_sum, 0, 2 * 128 * 4, stream);
    bn_stats_kernel<<<512, 256, 0, stream>>>(fc2a_out, bn_sum, bn_sumsq, N_NODES);
    bn_finalize_kernel<<<1, 128, 0, stream>>>(bn_sum, bn_sumsq, gamma, beta, bn_a, bn_b, N_NODES);
    {
        int t4 = N_NODES * BN_DIM / 4;
        bn_apply_kernel<<<(t4 + 255) / 256, 256, 0, stream>>>(fc2a_out, bn_a, bn_b, t4);
    }

    // ---- fc2b: 128 -> 19 (fp32, skinny) -> logits
    {
        dim3 grid((N_LABELS + 63) / 64, (N_NODES + 63) / 64);
        gemm_kernel<<<grid, 256, 0, stream>>>(fc2a_out, fc2bW, fc2bb, logits,
                                              N_NODES, BN_DIM, N_LABELS);
    }

    // ---- log_softmax -> out
    logsoftmax_kernel<<<(N_NODES + 255) / 256, 256, 0, stream>>>(logits, out, N_NODES);
}

// Round 5
// 896.958 us; speedup vs baseline: 12.9050x; 1.1024x over previous
//
#include <hip/hip_runtime.h>
#include <hip/hip_bf16.h>

#define N_NODES 100000
#define N_EDGES 1600000
#define F_IN_DIM 100
#define F_IN_PAD 104     // padded bf16 row stride (13 x 16B chunks)
#define H_DIM 256
#define BN_DIM 128
#define N_LABELS 19
#define BN_EPS 1e-5f

#define SCAN_CHUNK 2048

typedef __attribute__((ext_vector_type(8))) short bf16x8;   // 4 VGPRs, MFMA A/B frag / 16B
typedef __attribute__((ext_vector_type(4))) short s16x4;    // 8B
typedef __attribute__((ext_vector_type(4))) float f32x4;    // MFMA C/D frag

static __device__ inline short f2bf(float f) {
    __hip_bfloat16 h = __float2bfloat16(f);
    return *(short*)&h;
}
static __device__ inline float bf2f(short s) {
    unsigned u = ((unsigned)(unsigned short)s) << 16;
    return __builtin_bit_cast(float, u);
}

// ---------------------------------------------------------------- CSR build
__global__ void hist_kernel(const int* __restrict__ dst, int* __restrict__ indeg, int E) {
    int e = blockIdx.x * blockDim.x + threadIdx.x;
    if (e < E) atomicAdd(&indeg[dst[e]], 1);
}

__global__ void scan_partial(const int* __restrict__ in, int* __restrict__ blocksum, int n) {
    __shared__ int ls[256];
    int base = blockIdx.x * SCAN_CHUNK;
    int s = 0;
    for (int i = threadIdx.x; i < SCAN_CHUNK; i += 256) {
        int g = base + i;
        s += (g < n) ? in[g] : 0;
    }
    ls[threadIdx.x] = s;
    __syncthreads();
    for (int off = 128; off > 0; off >>= 1) {
        if (threadIdx.x < off) ls[threadIdx.x] += ls[threadIdx.x + off];
        __syncthreads();
    }
    if (threadIdx.x == 0) blocksum[blockIdx.x] = ls[0];
}

__global__ void scan_blocks(int* __restrict__ blocksum, int nb) {
    if (threadIdx.x == 0 && blockIdx.x == 0) {
        int acc = 0;
        for (int i = 0; i < nb; i++) { int v = blocksum[i]; blocksum[i] = acc; acc += v; }
    }
}

__global__ void scan_final(const int* __restrict__ in, const int* __restrict__ blocksum,
                           int* __restrict__ row_start, int* __restrict__ cursor,
                           int n, int total) {
    __shared__ int ts[256];
    int base = blockIdx.x * SCAN_CHUNK;
    int tid = threadIdx.x;
    int loc[8];
    int s = 0;
    int b0 = base + tid * 8;
    #pragma unroll
    for (int j = 0; j < 8; j++) {
        int g = b0 + j;
        int v = (g < n) ? in[g] : 0;
        loc[j] = s; s += v;
    }
    ts[tid] = s;
    __syncthreads();
    for (int off = 1; off < 256; off <<= 1) {
        int v = ts[tid];
        int add = (tid >= off) ? ts[tid - off] : 0;
        __syncthreads();
        ts[tid] = v + add;
        __syncthreads();
    }
    int texc = (tid > 0) ? ts[tid - 1] : 0;
    int boff = blocksum[blockIdx.x];
    #pragma unroll
    for (int j = 0; j < 8; j++) {
        int g = b0 + j;
        if (g < n) { int v = boff + texc + loc[j]; row_start[g] = v; cursor[g] = v; }
    }
    if (blockIdx.x == 0 && tid == 0) row_start[n] = total;
}

__global__ void fill_csr(const int* __restrict__ src, const int* __restrict__ dst,
                         int* __restrict__ cursor, int* __restrict__ src_sorted, int E) {
    int e = blockIdx.x * blockDim.x + threadIdx.x;
    if (e < E) {
        int pos = atomicAdd(&cursor[dst[e]], 1);
        src_sorted[pos] = src[e];
    }
}

__global__ void dinv_kernel(const int* __restrict__ indeg, float* __restrict__ dinv, int n) {
    int i = blockIdx.x * blockDim.x + threadIdx.x;
    if (i < n) dinv[i] = rsqrtf((float)indeg[i] + 1.0f);
}

// ---------------------------------------------------------------- weight pack
// Wt[n][kp] = bf16(W[k][n]) for k<K else 0; row stride Kp (zero-padded).
__global__ void pack_wt(const float* __restrict__ W, short* __restrict__ Wt,
                        int K, int N, int Kp) {
    int idx = blockIdx.x * blockDim.x + threadIdx.x;
    if (idx >= N * Kp) return;
    int n = idx / Kp, k = idx - n * Kp;
    Wt[idx] = (k < K) ? f2bf(W[(size_t)k * N + n]) : (short)0;
}

// ---------------------------------------------------------------- MFMA GEMM
// C[M x Nout] = A[M x K] @ Wt^T  (Wt is [Nout x Kp] bf16, zero-padded)
// A is fp32 (ABF16=0, optional clip) or bf16 (ABF16=1) with row stride strideA.
// Output bf16 (OBF16=1, zeros in pad cols) or fp32.
// 128x128 tile, 256 threads (4 waves), each wave 64x64 = 4x4 frags of 16x16x32.
#define BKP 40  // padded LDS row stride in shorts (80B: 16B-aligned, conflict-free)
template<int ABF16, int OBF16>
__global__ __launch_bounds__(256) void gemm_mfma(
    const void* __restrict__ Av, const short* __restrict__ Wt,
    const float* __restrict__ bias, const float* __restrict__ rowscale,
    void* __restrict__ Cv, int M, int K, int Kp, int Nout,
    int strideA, int strideC, int relu, int doclip)
{
    __shared__ __align__(16) short As[128][BKP];
    __shared__ __align__(16) short Bs[128][BKP];

    int tid = threadIdx.x;
    int wid = tid >> 6;
    int lane = tid & 63;
    int quad = lane >> 4;
    int l15 = lane & 15;
    int wave_m = (wid & 1) * 64;
    int wave_n = (wid >> 1) * 64;
    int rowBase = blockIdx.y * 128;
    int colBase = blockIdx.x * 128;

    f32x4 acc[4][4];
    #pragma unroll
    for (int i = 0; i < 4; i++)
        #pragma unroll
        for (int j = 0; j < 4; j++)
            acc[i][j] = (f32x4){0.f, 0.f, 0.f, 0.f};

    for (int k0 = 0; k0 < K; k0 += 32) {
        if (ABF16) {
            const short* A = (const short*)Av;
            #pragma unroll
            for (int i = 0; i < 2; i++) {
                int ch = tid + i * 256;            // 512 chunks of 8 shorts
                int r = ch >> 2, c8 = (ch & 3) << 3;
                int gr = rowBase + r, gk = k0 + c8;
                bf16x8 o = (bf16x8){0,0,0,0,0,0,0,0};
                if (gr < M && gk < strideA)
                    o = *(const bf16x8*)(A + (size_t)gr * strideA + gk);
                *(bf16x8*)(&As[r][c8]) = o;
            }
        } else {
            const float* A = (const float*)Av;
            #pragma unroll
            for (int i = 0; i < 4; i++) {
                int ch = tid + i * 256;            // 1024 float4 chunks
                int r = ch >> 3, c4 = (ch & 7) << 2;
                int gr = rowBase + r, gk = k0 + c4;
                float4 v = make_float4(0.f, 0.f, 0.f, 0.f);
                if (gr < M && gk < K)
                    v = *(const float4*)(A + (size_t)gr * strideA + gk);
                if (doclip) {
                    v.x = fminf(fmaxf(v.x, -0.4f), 0.4f);
                    v.y = fminf(fmaxf(v.y, -0.4f), 0.4f);
                    v.z = fminf(fmaxf(v.z, -0.4f), 0.4f);
                    v.w = fminf(fmaxf(v.w, -0.4f), 0.4f);
                }
                s16x4 o = (s16x4){f2bf(v.x), f2bf(v.y), f2bf(v.z), f2bf(v.w)};
                *(s16x4*)(&As[r][c4]) = o;
            }
        }
        #pragma unroll
        for (int i = 0; i < 2; i++) {
            int ch = tid + i * 256;
            int n = ch >> 2, c8 = (ch & 3) << 3;
            int gn = colBase + n, gk = k0 + c8;
            bf16x8 o = (bf16x8){0,0,0,0,0,0,0,0};
            if (gn < Nout && gk < Kp)
                o = *(const bf16x8*)(Wt + (size_t)gn * Kp + gk);
            *(bf16x8*)(&Bs[n][c8]) = o;
        }
        __syncthreads();

        bf16x8 a[4], b[4];
        #pragma unroll
        for (int im = 0; im < 4; im++)
            a[im] = *(const bf16x8*)(&As[wave_m + im * 16 + l15][quad * 8]);
        #pragma unroll
        for (int in = 0; in < 4; in++)
            b[in] = *(const bf16x8*)(&Bs[wave_n + in * 16 + l15][quad * 8]);
        #pragma unroll
        for (int im = 0; im < 4; im++)
            #pragma unroll
            for (int in = 0; in < 4; in++)
                acc[im][in] = __builtin_amdgcn_mfma_f32_16x16x32_bf16(
                    a[im], b[in], acc[im][in], 0, 0, 0);
        __syncthreads();
    }

    // ---- epilogue: C/D layout col=lane&15, row=quad*4+reg
    #pragma unroll
    for (int im = 0; im < 4; im++) {
        #pragma unroll
        for (int reg = 0; reg < 4; reg++) {
            int row = rowBase + wave_m + im * 16 + quad * 4 + reg;
            if (row >= M) continue;
            float rs = rowscale ? rowscale[row] : 1.f;
            #pragma unroll
            for (int in = 0; in < 4; in++) {
                int col = colBase + wave_n + in * 16 + l15;
                float v = 0.f;
                if (col < Nout) {
                    v = acc[im][in][reg];
                    if (bias) v += bias[col];
                    v *= rs;
                    if (relu) v = fmaxf(v, 0.f);
                }
                if (OBF16) {
                    if (col < strideC)
                        ((short*)Cv)[(size_t)row * strideC + col] = f2bf(v);
                } else {
                    if (col < Nout)
                        ((float*)Cv)[(size_t)row * strideC + col] = v;
                }
            }
        }
    }
}

// ---------------------------------------------------------------- gather aggregation (bf16)
// acc = sum_{e in in(d)} xws[src[e]]; self = xws[d]; di = dinv[d]
// MODE 0: out = relu(di*(acc+self) + bias)           (conv1)
// MODE 1: out = di * relu(di*(acc+self) + bias)      (conv2: pre-folds next layer's dinv_s)
// MODE 2: out = di * (acc+self)                      (conv3 pre-aggregation)
// bf16 in/out, fp32 accumulate. T lanes per node, 16B (8-col) chunk per lane.
template<int F, int STRIDE, int T, int MODE>
__global__ void gather_kernel(const short* __restrict__ xws,
                              const int* __restrict__ row_start,
                              const int* __restrict__ src_sorted,
                              const float* __restrict__ dinv,
                              const float* __restrict__ bias,
                              short* __restrict__ out, int n)
{
    constexpr int CHUNKS = STRIDE / 8;
    int group = (blockIdx.x * blockDim.x + threadIdx.x) / T;
    int lane = threadIdx.x % T;
    if (group >= n) return;
    int d = group;
    int e0 = row_start[d], e1 = row_start[d + 1];
    bool active = (lane < CHUNKS);
    int coff = lane * 8;
    float acc[8] = {};
    for (int e = e0; e < e1; e++) {
        int s = src_sorted[e];
        if (active) {
            bf16x8 v = *(const bf16x8*)(xws + (size_t)s * STRIDE + coff);
            #pragma unroll
            for (int j = 0; j < 8; j++) acc[j] += bf2f(v[j]);
        }
    }
    if (active) {
        bf16x8 xv = *(const bf16x8*)(xws + (size_t)d * STRIDE + coff);
        float di = dinv[d];
        bf16x8 o;
        #pragma unroll
        for (int j = 0; j < 8; j++) {
            int col = coff + j;
            float v = 0.f;
            if (col < F) {
                v = di * (acc[j] + bf2f(xv[j]));
                if (MODE == 0) v = fmaxf(v + bias[col], 0.f);
                if (MODE == 1) v = di * fmaxf(v + bias[col], 0.f);
            }
            o[j] = f2bf(v);
        }
        *(bf16x8*)(out + (size_t)d * STRIDE + coff) = o;
    }
}

// ---------------------------------------------------------------- BN stats
__global__ void bn_stats_kernel(const float* __restrict__ h,
                                float* __restrict__ sum, float* __restrict__ sumsq, int Ntot)
{
    int c = threadIdx.x & 127;
    int rpb = blockDim.x >> 7;
    int r0 = blockIdx.x * rpb + (threadIdx.x >> 7);
    int stride = gridDim.x * rpb;
    float s = 0.f, ss = 0.f;
    for (int r = r0; r < Ntot; r += stride) {
        float v = h[(size_t)r * BN_DIM + c];
        s += v; ss += v * v;
    }
    __shared__ float ls[256], lss[256];
    ls[threadIdx.x] = s; lss[threadIdx.x] = ss;
    __syncthreads();
    if (threadIdx.x < 128) {
        s = ls[threadIdx.x] + ls[threadIdx.x + 128];
        ss = lss[threadIdx.x] + lss[threadIdx.x + 128];
        atomicAdd(&sum[c], s);
        atomicAdd(&sumsq[c], ss);
    }
}

__global__ void bn_finalize_kernel(const float* __restrict__ sum, const float* __restrict__ sumsq,
                                   const float* __restrict__ gamma, const float* __restrict__ beta,
                                   float* __restrict__ a, float* __restrict__ b, int Ntot)
{
    int c = threadIdx.x;
    float inv_n = 1.0f / (float)Ntot;
    float mu = sum[c] * inv_n;
    float var = sumsq[c] * inv_n - mu * mu;
    float ai = gamma[c] * rsqrtf(var + BN_EPS);
    a[c] = ai;
    b[c] = beta[c] - mu * ai;
}

// ---------------------------------------------------------------- fused BN-apply + fc2b + log_softmax
// One thread per row: h_bn = relu(h*a + b); logits = h_bn @ W + bias; out = log_softmax(logits).
__global__ __launch_bounds__(256) void fc2b_fused_kernel(
    const float* __restrict__ h, const float* __restrict__ bn_a, const float* __restrict__ bn_b,
    const float* __restrict__ W, const float* __restrict__ bias,
    float* __restrict__ out, int Ntot)
{
    __shared__ float Ws[BN_DIM][N_LABELS + 1];
    __shared__ float as[BN_DIM], bs[BN_DIM];
    for (int i = threadIdx.x; i < BN_DIM * N_LABELS; i += 256) {
        int k = i / N_LABELS, j = i - k * N_LABELS;
        Ws[k][j] = W[i];
    }
    if (threadIdx.x < BN_DIM) {
        as[threadIdx.x] = bn_a[threadIdx.x];
        bs[threadIdx.x] = bn_b[threadIdx.x];
    }
    __syncthreads();

    int r = blockIdx.x * 256 + threadIdx.x;
    if (r >= Ntot) return;

    float acc[N_LABELS];
    #pragma unroll
    for (int j = 0; j < N_LABELS; j++) acc[j] = bias[j];

    const float* hr = h + (size_t)r * BN_DIM;
    #pragma unroll
    for (int k0 = 0; k0 < BN_DIM; k0 += 4) {
        float4 v = *(const float4*)(hr + k0);
        v.x = fmaxf(v.x * as[k0 + 0] + bs[k0 + 0], 0.f);
        v.y = fmaxf(v.y * as[k0 + 1] + bs[k0 + 1], 0.f);
        v.z = fmaxf(v.z * as[k0 + 2] + bs[k0 + 2], 0.f);
        v.w = fmaxf(v.w * as[k0 + 3] + bs[k0 + 3], 0.f);
        #pragma unroll
        for (int j = 0; j < N_LABELS; j++) {
            acc[j] = fmaf(v.x, Ws[k0 + 0][j],
                     fmaf(v.y, Ws[k0 + 1][j],
                     fmaf(v.z, Ws[k0 + 2][j],
                     fmaf(v.w, Ws[k0 + 3][j], acc[j]))));
        }
    }

    float m = acc[0];
    #pragma unroll
    for (int j = 1; j < N_LABELS; j++) m = fmaxf(m, acc[j]);
    float s = 0.f;
    #pragma unroll
    for (int j = 0; j < N_LABELS; j++) s += expf(acc[j] - m);
    float lse = m + logf(s);
    float* o = out + (size_t)r * N_LABELS;
    #pragma unroll
    for (int j = 0; j < N_LABELS; j++) o[j] = acc[j] - lse;
}

// ================================================================ launch
extern "C" void kernel_launch(void* const* d_in, const int* in_sizes, int n_in,
                              void* d_out, int out_size, void* d_ws, size_t ws_size,
                              hipStream_t stream)
{
    const float* x      = (const float*)d_in[0];
    const int*   ei     = (const int*)d_in[1];
    const float* W1     = (const float*)d_in[2];
    const float* b1     = (const float*)d_in[3];
    const float* W2     = (const float*)d_in[4];
    const float* b2     = (const float*)d_in[5];
    const float* W3     = (const float*)d_in[6];
    const float* b3     = (const float*)d_in[7];
    const float* fc1_W  = (const float*)d_in[8];
    const float* fc1_b  = (const float*)d_in[9];
    const float* fc2aW  = (const float*)d_in[10];
    const float* fc2ab  = (const float*)d_in[11];
    const float* gamma  = (const float*)d_in[12];
    const float* beta   = (const float*)d_in[13];
    const float* fc2bW  = (const float*)d_in[14];
    const float* fc2bb  = (const float*)d_in[15];
    float* out = (float*)d_out;

    const int* src = ei;
    const int* dst = ei + N_EDGES;

    char* w = (char*)d_ws;
    float* dinv       = (float*)w;  w += ((size_t)N_NODES * 4 + 255) / 256 * 256;
    int*   indeg      = (int*)w;    w += ((size_t)N_NODES * 4 + 255) / 256 * 256;
    int*   row_start  = (int*)w;    w += ((size_t)(N_NODES + 1) * 4 + 255) / 256 * 256;
    int*   cursor     = (int*)w;    w += ((size_t)N_NODES * 4 + 255) / 256 * 256;
    int*   blocksum   = (int*)w;    w += 4096;
    float* bn_sum     = (float*)w;  w += 128 * 4;
    float* bn_sumsq   = (float*)w;  w += 128 * 4;
    float* bn_a       = (float*)w;  w += 128 * 4;
    float* bn_b       = (float*)w;  w += 128 * 4;
    short* Wt1        = (short*)w;  w += ((size_t)F_IN_DIM * F_IN_PAD * 2 + 255) / 256 * 256;
    short* Wt2        = (short*)w;  w += ((size_t)F_IN_DIM * F_IN_PAD * 2 + 255) / 256 * 256;
    short* Wt3        = (short*)w;  w += ((size_t)H_DIM * F_IN_PAD * 2 + 255) / 256 * 256;
    short* Wtf1       = (short*)w;  w += ((size_t)H_DIM * H_DIM * 2 + 255) / 256 * 256;
    short* Wtf2a      = (short*)w;  w += ((size_t)BN_DIM * H_DIM * 2 + 255) / 256 * 256;
    int*   src_sorted = (int*)w;    w += ((size_t)N_EDGES * 4 + 255) / 256 * 256;
    short* xws100     = (short*)w;  w += ((size_t)N_NODES * F_IN_PAD * 2 + 255) / 256 * 256;
    short* agg100     = (short*)w;  w += ((size_t)N_NODES * F_IN_PAD * 2 + 255) / 256 * 256;
    short* big1       = (short*)w;  w += ((size_t)N_NODES * H_DIM * 2 + 255) / 256 * 256;
    short* big2       = (short*)w;  w += ((size_t)N_NODES * H_DIM * 2 + 255) / 256 * 256;
    float* fc2a_out   = (float*)w;

    const int nScanBlocks = (N_NODES + SCAN_CHUNK - 1) / SCAN_CHUNK;  // 49

    // ---- CSR build + dinv
    hipMemsetAsync(indeg, 0, (size_t)N_NODES * 4, stream);
    hist_kernel<<<(N_EDGES + 255) / 256, 256, 0, stream>>>(dst, indeg, N_EDGES);
    scan_partial<<<nScanBlocks, 256, 0, stream>>>(indeg, blocksum, N_NODES);
    scan_blocks<<<1, 64, 0, stream>>>(blocksum, nScanBlocks);
    scan_final<<<nScanBlocks, 256, 0, stream>>>(indeg, blocksum, row_start, cursor, N_NODES, N_EDGES);
    fill_csr<<<(N_EDGES + 255) / 256, 256, 0, stream>>>(src, dst, cursor, src_sorted, N_EDGES);
    dinv_kernel<<<(N_NODES + 255) / 256, 256, 0, stream>>>(indeg, dinv, N_NODES);

    // ---- pack weights (transpose + bf16 + zero-pad K)
    pack_wt<<<(F_IN_DIM * F_IN_PAD + 255) / 256, 256, 0, stream>>>(W1, Wt1, F_IN_DIM, F_IN_DIM, F_IN_PAD);
    pack_wt<<<(F_IN_DIM * F_IN_PAD + 255) / 256, 256, 0, stream>>>(W2, Wt2, F_IN_DIM, F_IN_DIM, F_IN_PAD);
    pack_wt<<<(H_DIM * F_IN_PAD + 255) / 256, 256, 0, stream>>>(W3, Wt3, F_IN_DIM, H_DIM, F_IN_PAD);
    pack_wt<<<(H_DIM * H_DIM + 255) / 256, 256, 0, stream>>>(fc1_W, Wtf1, H_DIM, H_DIM, H_DIM);
    pack_wt<<<(BN_DIM * H_DIM + 255) / 256, 256, 0, stream>>>(fc2aW, Wtf2a, H_DIM, BN_DIM, H_DIM);

    dim3 g100(1, (N_NODES + 127) / 128);
    dim3 g256(2, (N_NODES + 127) / 128);
    int gatherBlocks = (N_NODES * 16 + 255) / 256;

    // ---- conv1: xw = clip(x) @ W1, rowscale dinv -> xws100; gather -> h1 (agg100)
    gemm_mfma<0, 1><<<g100, 256, 0, stream>>>(x, Wt1, nullptr, dinv, xws100,
        N_NODES, F_IN_DIM, F_IN_PAD, F_IN_DIM, F_IN_DIM, F_IN_PAD, 0, 1);
    gather_kernel<F_IN_DIM, F_IN_PAD, 16, 0><<<gatherBlocks, 256, 0, stream>>>(
        xws100, row_start, src_sorted, dinv, b1, agg100, N_NODES);

    // ---- conv2: xw = h1 @ W2, rowscale dinv -> xws100; gather (postscale dinv) -> h2' (agg100)
    gemm_mfma<1, 1><<<g100, 256, 0, stream>>>(agg100, Wt2, nullptr, dinv, xws100,
        N_NODES, F_IN_DIM, F_IN_PAD, F_IN_DIM, F_IN_PAD, F_IN_PAD, 0, 0);
    gather_kernel<F_IN_DIM, F_IN_PAD, 16, 1><<<gatherBlocks, 256, 0, stream>>>(
        xws100, row_start, src_sorted, dinv, b2, agg100, N_NODES);

    // ---- conv3 (aggregate-first): g = dinv_d*(sum h2' + self) -> xws100; h3 = relu(g@W3+b3) -> big1
    gather_kernel<F_IN_DIM, F_IN_PAD, 16, 2><<<gatherBlocks, 256, 0, stream>>>(
        agg100, row_start, src_sorted, dinv, nullptr, xws100, N_NODES);
    gemm_mfma<1, 1><<<g256, 256, 0, stream>>>(xws100, Wt3, b3, nullptr, big1,
        N_NODES, F_IN_DIM, F_IN_PAD, H_DIM, F_IN_PAD, H_DIM, 1, 0);

    // ---- fc1: 256 -> 256, relu -> big2
    gemm_mfma<1, 1><<<g256, 256, 0, stream>>>(big1, Wtf1, fc1_b, nullptr, big2,
        N_NODES, H_DIM, H_DIM, H_DIM, H_DIM, H_DIM, 1, 0);

    // ---- fc2a: 256 -> 128 -> fc2a_out (fp32)
    gemm_mfma<1, 0><<<g100, 256, 0, stream>>>(big2, Wtf2a, fc2ab, nullptr, fc2a_out,
        N_NODES, H_DIM, H_DIM, BN_DIM, H_DIM, BN_DIM, 0, 0);

    // ---- BN stats
    hipMemsetAsync(bn_sum, 0, 2 * 128 * 4, stream);
    bn_stats_kernel<<<512, 256, 0, stream>>>(fc2a_out, bn_sum, bn_sumsq, N_NODES);
    bn_finalize_kernel<<<1, 128, 0, stream>>>(bn_sum, bn_sumsq, gamma, beta, bn_a, bn_b, N_NODES);

    // ---- fused BN-apply + fc2b + log_softmax -> out
    fc2b_fused_kernel<<<(N_NODES + 255) / 256, 256, 0, stream>>>(
        fc2a_out, bn_a, bn_b, fc2bW, fc2bb, out, N_NODES);
}

// Round 6
// 752.412 us; speedup vs baseline: 15.3842x; 1.1921x over previous
//
#include <hip/hip_runtime.h>
#include <hip/hip_bf16.h>

#define N_NODES 100000
#define N_EDGES 1600000
#define F_IN_DIM 100
#define F_IN_PAD 104     // padded bf16 row stride (13 x 16B chunks)
#define H_DIM 256
#define BN_DIM 128
#define N_LABELS 19
#define BN_EPS 1e-5f

// bucket-partitioned CSR build
#define BUCKET_SHIFT 8
#define NB 391           // ceil(100000 / 256) buckets of 256 nodes
#define EPB 4096         // edges per partition block
#define PB 391           // ceil(1600000 / 4096) partition blocks

typedef __attribute__((ext_vector_type(8))) short bf16x8;   // 4 VGPRs, MFMA A/B frag / 16B
typedef __attribute__((ext_vector_type(4))) short s16x4;    // 8B
typedef __attribute__((ext_vector_type(4))) float f32x4;    // MFMA C/D frag

static __device__ inline short f2bf(float f) {
    __hip_bfloat16 h = __float2bfloat16(f);
    return *(short*)&h;
}
static __device__ inline float bf2f(short s) {
    unsigned u = ((unsigned)(unsigned short)s) << 16;
    return __builtin_bit_cast(float, u);
}

// ---------------------------------------------------------------- CSR build (bucketed)
// P1: per-block bucket histogram (LDS atomics only)
__global__ __launch_bounds__(256) void part_hist_kernel(const int* __restrict__ dst,
                                                        int* __restrict__ part_hist, int E)
{
    __shared__ int h[NB];
    int tid = threadIdx.x;
    for (int i = tid; i < NB; i += 256) h[i] = 0;
    __syncthreads();
    int base = blockIdx.x * EPB;
    int end = min(base + EPB, E);
    for (int e = base + tid; e < end; e += 256)
        atomicAdd(&h[dst[e] >> BUCKET_SHIFT], 1);
    __syncthreads();
    for (int i = tid; i < NB; i += 256) part_hist[blockIdx.x * NB + i] = h[i];
}

// S1: bucket totals
__global__ __launch_bounds__(512) void bucket_total_kernel(const int* __restrict__ part_hist,
                                                           int* __restrict__ bucket_total)
{
    __shared__ int ls[512];
    int b = blockIdx.x;
    int s = 0;
    for (int p = threadIdx.x; p < PB; p += 512) s += part_hist[p * NB + b];
    ls[threadIdx.x] = s;
    __syncthreads();
    for (int off = 256; off > 0; off >>= 1) {
        if (threadIdx.x < off) ls[threadIdx.x] += ls[threadIdx.x + off];
        __syncthreads();
    }
    if (threadIdx.x == 0) bucket_total[b] = ls[0];
}

// S2: exclusive scan of bucket totals -> bucket_base[NB+1]
__global__ __launch_bounds__(512) void bucket_scan_kernel(const int* __restrict__ bucket_total,
                                                          int* __restrict__ bucket_base)
{
    __shared__ int ls[512];
    int tid = threadIdx.x;
    ls[tid] = (tid < NB) ? bucket_total[tid] : 0;
    __syncthreads();
    for (int off = 1; off < 512; off <<= 1) {
        int v = ls[tid];
        int add = (tid >= off) ? ls[tid - off] : 0;
        __syncthreads();
        ls[tid] = v + add;
        __syncthreads();
    }
    if (tid < NB) bucket_base[tid] = (tid > 0) ? ls[tid - 1] : 0;
    if (tid == 0) bucket_base[NB] = ls[NB - 1];
}

// S3: per bucket, exclusive scan over partition blocks -> global write offsets (in place)
__global__ __launch_bounds__(512) void part_offset_kernel(int* __restrict__ part_hist,
                                                          const int* __restrict__ bucket_base)
{
    __shared__ int ls[512];
    int b = blockIdx.x;
    int tid = threadIdx.x;
    int v = (tid < PB) ? part_hist[tid * NB + b] : 0;
    ls[tid] = v;
    __syncthreads();
    for (int off = 1; off < 512; off <<= 1) {
        int x = ls[tid];
        int add = (tid >= off) ? ls[tid - off] : 0;
        __syncthreads();
        ls[tid] = x + add;
        __syncthreads();
    }
    if (tid < PB) part_hist[tid * NB + b] = bucket_base[b] + ((tid > 0) ? ls[tid - 1] : 0);
}

// P2: partition edges into bucket-contiguous (src,dst) pairs
__global__ __launch_bounds__(256) void partition_kernel(const int* __restrict__ src,
                                                        const int* __restrict__ dst,
                                                        const int* __restrict__ part_hist,
                                                        int2* __restrict__ ep, int E)
{
    __shared__ int cur[NB];
    int tid = threadIdx.x;
    for (int i = tid; i < NB; i += 256) cur[i] = part_hist[blockIdx.x * NB + i];
    __syncthreads();
    int base = blockIdx.x * EPB;
    int end = min(base + EPB, E);
    for (int e = base + tid; e < end; e += 256) {
        int d = dst[e];
        int s = src[e];
        int pos = atomicAdd(&cur[d >> BUCKET_SHIFT], 1);
        ep[pos] = make_int2(s, d);
    }
}

// P3: per-bucket CSR finish: node hist + scan -> row_start, dinv, src_sorted
__global__ __launch_bounds__(256) void bucket_csr_kernel(const int2* __restrict__ ep,
                                                         const int* __restrict__ bucket_base,
                                                         int* __restrict__ row_start,
                                                         float* __restrict__ dinv,
                                                         int* __restrict__ src_sorted, int N, int E)
{
    __shared__ int h[256], sc[256], cur[256];
    int b = blockIdx.x;
    int tid = threadIdx.x;
    int e0 = bucket_base[b], e1 = bucket_base[b + 1];
    int node0 = b << BUCKET_SHIFT;
    int nn = min(256, N - node0);

    h[tid] = 0;
    __syncthreads();
    for (int e = e0 + tid; e < e1; e += 256)
        atomicAdd(&h[ep[e].y & 255], 1);
    __syncthreads();

    sc[tid] = h[tid];
    __syncthreads();
    for (int off = 1; off < 256; off <<= 1) {
        int v = sc[tid];
        int add = (tid >= off) ? sc[tid - off] : 0;
        __syncthreads();
        sc[tid] = v + add;
        __syncthreads();
    }
    int excl = e0 + ((tid > 0) ? sc[tid - 1] : 0);
    if (tid < nn) {
        row_start[node0 + tid] = excl;
        dinv[node0 + tid] = rsqrtf((float)h[tid] + 1.0f);
    }
    cur[tid] = excl;
    __syncthreads();
    for (int e = e0 + tid; e < e1; e += 256) {
        int2 v = ep[e];
        int pos = atomicAdd(&cur[v.y & 255], 1);
        src_sorted[pos] = v.x;
    }
    if (b == 0 && tid == 0) row_start[N] = E;
}

// ---------------------------------------------------------------- weight pack
// Wt[n][kp] = bf16(W[k][n]) for k<K else 0; row stride Kp (zero-padded).
__global__ void pack_wt(const float* __restrict__ W, short* __restrict__ Wt,
                        int K, int N, int Kp) {
    int idx = blockIdx.x * blockDim.x + threadIdx.x;
    if (idx >= N * Kp) return;
    int n = idx / Kp, k = idx - n * Kp;
    Wt[idx] = (k < K) ? f2bf(W[(size_t)k * N + n]) : (short)0;
}

// ---------------------------------------------------------------- MFMA GEMM
// C[M x Nout] = A[M x K] @ Wt^T  (Wt is [Nout x Kp] bf16, zero-padded)
// A is fp32 (ABF16=0, optional clip) or bf16 (ABF16=1) with row stride strideA.
// Output bf16 (OBF16=1, zeros in pad cols) or fp32.
// 128x128 tile, 256 threads (4 waves), each wave 64x64 = 4x4 frags of 16x16x32.
#define BKP 40  // padded LDS row stride in shorts (80B: 16B-aligned, conflict-free)
template<int ABF16, int OBF16>
__global__ __launch_bounds__(256) void gemm_mfma(
    const void* __restrict__ Av, const short* __restrict__ Wt,
    const float* __restrict__ bias, const float* __restrict__ rowscale,
    void* __restrict__ Cv, int M, int K, int Kp, int Nout,
    int strideA, int strideC, int relu, int doclip)
{
    __shared__ __align__(16) short As[128][BKP];
    __shared__ __align__(16) short Bs[128][BKP];

    int tid = threadIdx.x;
    int wid = tid >> 6;
    int lane = tid & 63;
    int quad = lane >> 4;
    int l15 = lane & 15;
    int wave_m = (wid & 1) * 64;
    int wave_n = (wid >> 1) * 64;
    int rowBase = blockIdx.y * 128;
    int colBase = blockIdx.x * 128;

    f32x4 acc[4][4];
    #pragma unroll
    for (int i = 0; i < 4; i++)
        #pragma unroll
        for (int j = 0; j < 4; j++)
            acc[i][j] = (f32x4){0.f, 0.f, 0.f, 0.f};

    for (int k0 = 0; k0 < K; k0 += 32) {
        if (ABF16) {
            const short* A = (const short*)Av;
            #pragma unroll
            for (int i = 0; i < 2; i++) {
                int ch = tid + i * 256;            // 512 chunks of 8 shorts
                int r = ch >> 2, c8 = (ch & 3) << 3;
                int gr = rowBase + r, gk = k0 + c8;
                bf16x8 o = (bf16x8){0,0,0,0,0,0,0,0};
                if (gr < M && gk < strideA)
                    o = *(const bf16x8*)(A + (size_t)gr * strideA + gk);
                *(bf16x8*)(&As[r][c8]) = o;
            }
        } else {
            const float* A = (const float*)Av;
            #pragma unroll
            for (int i = 0; i < 4; i++) {
                int ch = tid + i * 256;            // 1024 float4 chunks
                int r = ch >> 3, c4 = (ch & 7) << 2;
                int gr = rowBase + r, gk = k0 + c4;
                float4 v = make_float4(0.f, 0.f, 0.f, 0.f);
                if (gr < M && gk < K)
                    v = *(const float4*)(A + (size_t)gr * strideA + gk);
                if (doclip) {
                    v.x = fminf(fmaxf(v.x, -0.4f), 0.4f);
                    v.y = fminf(fmaxf(v.y, -0.4f), 0.4f);
                    v.z = fminf(fmaxf(v.z, -0.4f), 0.4f);
                    v.w = fminf(fmaxf(v.w, -0.4f), 0.4f);
                }
                s16x4 o = (s16x4){f2bf(v.x), f2bf(v.y), f2bf(v.z), f2bf(v.w)};
                *(s16x4*)(&As[r][c4]) = o;
            }
        }
        #pragma unroll
        for (int i = 0; i < 2; i++) {
            int ch = tid + i * 256;
            int n = ch >> 2, c8 = (ch & 3) << 3;
            int gn = colBase + n, gk = k0 + c8;
            bf16x8 o = (bf16x8){0,0,0,0,0,0,0,0};
            if (gn < Nout && gk < Kp)
                o = *(const bf16x8*)(Wt + (size_t)gn * Kp + gk);
            *(bf16x8*)(&Bs[n][c8]) = o;
        }
        __syncthreads();

        bf16x8 a[4], b[4];
        #pragma unroll
        for (int im = 0; im < 4; im++)
            a[im] = *(const bf16x8*)(&As[wave_m + im * 16 + l15][quad * 8]);
        #pragma unroll
        for (int in = 0; in < 4; in++)
            b[in] = *(const bf16x8*)(&Bs[wave_n + in * 16 + l15][quad * 8]);
        #pragma unroll
        for (int im = 0; im < 4; im++)
            #pragma unroll
            for (int in = 0; in < 4; in++)
                acc[im][in] = __builtin_amdgcn_mfma_f32_16x16x32_bf16(
                    a[im], b[in], acc[im][in], 0, 0, 0);
        __syncthreads();
    }

    // ---- epilogue: C/D layout col=lane&15, row=quad*4+reg
    #pragma unroll
    for (int im = 0; im < 4; im++) {
        #pragma unroll
        for (int reg = 0; reg < 4; reg++) {
            int row = rowBase + wave_m + im * 16 + quad * 4 + reg;
            if (row >= M) continue;
            float rs = rowscale ? rowscale[row] : 1.f;
            #pragma unroll
            for (int in = 0; in < 4; in++) {
                int col = colBase + wave_n + in * 16 + l15;
                float v = 0.f;
                if (col < Nout) {
                    v = acc[im][in][reg];
                    if (bias) v += bias[col];
                    v *= rs;
                    if (relu) v = fmaxf(v, 0.f);
                }
                if (OBF16) {
                    if (col < strideC)
                        ((short*)Cv)[(size_t)row * strideC + col] = f2bf(v);
                } else {
                    if (col < Nout)
                        ((float*)Cv)[(size_t)row * strideC + col] = v;
                }
            }
        }
    }
}

// ---------------------------------------------------------------- gather aggregation (bf16)
// acc = sum_{e in in(d)} xws[src[e]]; self = xws[d]; di = dinv[d]
// MODE 0: out = relu(di*(acc+self) + bias)           (conv1)
// MODE 1: out = di * relu(di*(acc+self) + bias)      (conv2: pre-folds next layer's dinv_s)
// MODE 2: out = di * (acc+self)                      (conv3 pre-aggregation)
template<int F, int STRIDE, int T, int MODE>
__global__ void gather_kernel(const short* __restrict__ xws,
                              const int* __restrict__ row_start,
                              const int* __restrict__ src_sorted,
                              const float* __restrict__ dinv,
                              const float* __restrict__ bias,
                              short* __restrict__ out, int n)
{
    constexpr int CHUNKS = STRIDE / 8;
    int group = (blockIdx.x * blockDim.x + threadIdx.x) / T;
    int lane = threadIdx.x % T;
    if (group >= n) return;
    int d = group;
    int e0 = row_start[d], e1 = row_start[d + 1];
    bool active = (lane < CHUNKS);
    int coff = lane * 8;
    float acc[8] = {};
    for (int e = e0; e < e1; e++) {
        int s = src_sorted[e];
        if (active) {
            bf16x8 v = *(const bf16x8*)(xws + (size_t)s * STRIDE + coff);
            #pragma unroll
            for (int j = 0; j < 8; j++) acc[j] += bf2f(v[j]);
        }
    }
    if (active) {
        bf16x8 xv = *(const bf16x8*)(xws + (size_t)d * STRIDE + coff);
        float di = dinv[d];
        bf16x8 o;
        #pragma unroll
        for (int j = 0; j < 8; j++) {
            int col = coff + j;
            float v = 0.f;
            if (col < F) {
                v = di * (acc[j] + bf2f(xv[j]));
                if (MODE == 0) v = fmaxf(v + bias[col], 0.f);
                if (MODE == 1) v = di * fmaxf(v + bias[col], 0.f);
            }
            o[j] = f2bf(v);
        }
        *(bf16x8*)(out + (size_t)d * STRIDE + coff) = o;
    }
}

// ---------------------------------------------------------------- BN stats (bf16 input)
__global__ void bn_stats_kernel(const short* __restrict__ h,
                                float* __restrict__ sum, float* __restrict__ sumsq, int Ntot)
{
    int c = threadIdx.x & 127;
    int rpb = blockDim.x >> 7;
    int r0 = blockIdx.x * rpb + (threadIdx.x >> 7);
    int stride = gridDim.x * rpb;
    float s = 0.f, ss = 0.f;
    for (int r = r0; r < Ntot; r += stride) {
        float v = bf2f(h[(size_t)r * BN_DIM + c]);
        s += v; ss += v * v;
    }
    __shared__ float ls[256], lss[256];
    ls[threadIdx.x] = s; lss[threadIdx.x] = ss;
    __syncthreads();
    if (threadIdx.x < 128) {
        s = ls[threadIdx.x] + ls[threadIdx.x + 128];
        ss = lss[threadIdx.x] + lss[threadIdx.x + 128];
        atomicAdd(&sum[c], s);
        atomicAdd(&sumsq[c], ss);
    }
}

__global__ void bn_finalize_kernel(const float* __restrict__ sum, const float* __restrict__ sumsq,
                                   const float* __restrict__ gamma, const float* __restrict__ beta,
                                   float* __restrict__ a, float* __restrict__ b, int Ntot)
{
    int c = threadIdx.x;
    float inv_n = 1.0f / (float)Ntot;
    float mu = sum[c] * inv_n;
    float var = sumsq[c] * inv_n - mu * mu;
    float ai = gamma[c] * rsqrtf(var + BN_EPS);
    a[c] = ai;
    b[c] = beta[c] - mu * ai;
}

// ---------------------------------------------------------------- fused BN-apply + fc2b + log_softmax
// One thread per row (bf16 input): h_bn = relu(h*a + b); logits = h_bn @ W + bias; log_softmax.
__global__ __launch_bounds__(256) void fc2b_fused_kernel(
    const short* __restrict__ h, const float* __restrict__ bn_a, const float* __restrict__ bn_b,
    const float* __restrict__ W, const float* __restrict__ bias,
    float* __restrict__ out, int Ntot)
{
    __shared__ float Ws[BN_DIM][N_LABELS + 1];
    __shared__ float as[BN_DIM], bs[BN_DIM];
    for (int i = threadIdx.x; i < BN_DIM * N_LABELS; i += 256) {
        int k = i / N_LABELS, j = i - k * N_LABELS;
        Ws[k][j] = W[i];
    }
    if (threadIdx.x < BN_DIM) {
        as[threadIdx.x] = bn_a[threadIdx.x];
        bs[threadIdx.x] = bn_b[threadIdx.x];
    }
    __syncthreads();

    int r = blockIdx.x * 256 + threadIdx.x;
    if (r >= Ntot) return;

    float acc[N_LABELS];
    #pragma unroll
    for (int j = 0; j < N_LABELS; j++) acc[j] = bias[j];

    const short* hr = h + (size_t)r * BN_DIM;
    #pragma unroll
    for (int k0 = 0; k0 < BN_DIM; k0 += 8) {
        bf16x8 hv = *(const bf16x8*)(hr + k0);
        #pragma unroll
        for (int t = 0; t < 8; t++) {
            float v = fmaxf(bf2f(hv[t]) * as[k0 + t] + bs[k0 + t], 0.f);
            #pragma unroll
            for (int j = 0; j < N_LABELS; j++)
                acc[j] = fmaf(v, Ws[k0 + t][j], acc[j]);
        }
    }

    float m = acc[0];
    #pragma unroll
    for (int j = 1; j < N_LABELS; j++) m = fmaxf(m, acc[j]);
    float s = 0.f;
    #pragma unroll
    for (int j = 0; j < N_LABELS; j++) s += expf(acc[j] - m);
    float lse = m + logf(s);
    float* o = out + (size_t)r * N_LABELS;
    #pragma unroll
    for (int j = 0; j < N_LABELS; j++) o[j] = acc[j] - lse;
}

// ================================================================ launch
extern "C" void kernel_launch(void* const* d_in, const int* in_sizes, int n_in,
                              void* d_out, int out_size, void* d_ws, size_t ws_size,
                              hipStream_t stream)
{
    const float* x      = (const float*)d_in[0];
    const int*   ei     = (const int*)d_in[1];
    const float* W1     = (const float*)d_in[2];
    const float* b1     = (const float*)d_in[3];
    const float* W2     = (const float*)d_in[4];
    const float* b2     = (const float*)d_in[5];
    const float* W3     = (const float*)d_in[6];
    const float* b3     = (const float*)d_in[7];
    const float* fc1_W  = (const float*)d_in[8];
    const float* fc1_b  = (const float*)d_in[9];
    const float* fc2aW  = (const float*)d_in[10];
    const float* fc2ab  = (const float*)d_in[11];
    const float* gamma  = (const float*)d_in[12];
    const float* beta   = (const float*)d_in[13];
    const float* fc2bW  = (const float*)d_in[14];
    const float* fc2bb  = (const float*)d_in[15];
    float* out = (float*)d_out;

    const int* src = ei;
    const int* dst = ei + N_EDGES;

    char* w = (char*)d_ws;
    float* dinv        = (float*)w;  w += ((size_t)N_NODES * 4 + 255) / 256 * 256;
    int*   row_start   = (int*)w;    w += ((size_t)(N_NODES + 1) * 4 + 255) / 256 * 256;
    int*   part_hist   = (int*)w;    w += ((size_t)PB * NB * 4 + 255) / 256 * 256;
    int*   bucket_total= (int*)w;    w += ((size_t)NB * 4 + 255) / 256 * 256;
    int*   bucket_base = (int*)w;    w += ((size_t)(NB + 1) * 4 + 255) / 256 * 256;
    float* bn_sum      = (float*)w;  w += 128 * 4;
    float* bn_sumsq    = (float*)w;  w += 128 * 4;
    float* bn_a        = (float*)w;  w += 128 * 4;
    float* bn_b        = (float*)w;  w += 128 * 4;
    short* Wt1         = (short*)w;  w += ((size_t)F_IN_DIM * F_IN_PAD * 2 + 255) / 256 * 256;
    short* Wt2         = (short*)w;  w += ((size_t)F_IN_DIM * F_IN_PAD * 2 + 255) / 256 * 256;
    short* Wt3         = (short*)w;  w += ((size_t)H_DIM * F_IN_PAD * 2 + 255) / 256 * 256;
    short* Wtf1        = (short*)w;  w += ((size_t)H_DIM * H_DIM * 2 + 255) / 256 * 256;
    short* Wtf2a       = (short*)w;  w += ((size_t)BN_DIM * H_DIM * 2 + 255) / 256 * 256;
    int*   src_sorted  = (int*)w;    w += ((size_t)N_EDGES * 4 + 255) / 256 * 256;
    int2*  ep          = (int2*)w;   w += ((size_t)N_EDGES * 8 + 255) / 256 * 256;
    short* xws100      = (short*)w;  w += ((size_t)N_NODES * F_IN_PAD * 2 + 255) / 256 * 256;
    short* agg100      = (short*)w;  w += ((size_t)N_NODES * F_IN_PAD * 2 + 255) / 256 * 256;
    short* big1        = (short*)w;  w += ((size_t)N_NODES * H_DIM * 2 + 255) / 256 * 256;
    short* big2        = (short*)w;  w += ((size_t)N_NODES * H_DIM * 2 + 255) / 256 * 256;

    // ---- CSR build (bucket-partitioned, LDS atomics) + dinv
    part_hist_kernel<<<PB, 256, 0, stream>>>(dst, part_hist, N_EDGES);
    bucket_total_kernel<<<NB, 512, 0, stream>>>(part_hist, bucket_total);
    bucket_scan_kernel<<<1, 512, 0, stream>>>(bucket_total, bucket_base);
    part_offset_kernel<<<NB, 512, 0, stream>>>(part_hist, bucket_base);
    partition_kernel<<<PB, 256, 0, stream>>>(src, dst, part_hist, ep, N_EDGES);
    bucket_csr_kernel<<<NB, 256, 0, stream>>>(ep, bucket_base, row_start, dinv,
                                              src_sorted, N_NODES, N_EDGES);

    // ---- pack weights (transpose + bf16 + zero-pad K)
    pack_wt<<<(F_IN_DIM * F_IN_PAD + 255) / 256, 256, 0, stream>>>(W1, Wt1, F_IN_DIM, F_IN_DIM, F_IN_PAD);
    pack_wt<<<(F_IN_DIM * F_IN_PAD + 255) / 256, 256, 0, stream>>>(W2, Wt2, F_IN_DIM, F_IN_DIM, F_IN_PAD);
    pack_wt<<<(H_DIM * F_IN_PAD + 255) / 256, 256, 0, stream>>>(W3, Wt3, F_IN_DIM, H_DIM, F_IN_PAD);
    pack_wt<<<(H_DIM * H_DIM + 255) / 256, 256, 0, stream>>>(fc1_W, Wtf1, H_DIM, H_DIM, H_DIM);
    pack_wt<<<(BN_DIM * H_DIM + 255) / 256, 256, 0, stream>>>(fc2aW, Wtf2a, H_DIM, BN_DIM, H_DIM);

    dim3 g100(1, (N_NODES + 127) / 128);
    dim3 g256(2, (N_NODES + 127) / 128);
    int gatherBlocks = (N_NODES * 16 + 255) / 256;

    // ---- conv1: xw = clip(x) @ W1, rowscale dinv -> xws100; gather -> h1 (agg100)
    gemm_mfma<0, 1><<<g100, 256, 0, stream>>>(x, Wt1, nullptr, dinv, xws100,
        N_NODES, F_IN_DIM, F_IN_PAD, F_IN_DIM, F_IN_DIM, F_IN_PAD, 0, 1);
    gather_kernel<F_IN_DIM, F_IN_PAD, 16, 0><<<gatherBlocks, 256, 0, stream>>>(
        xws100, row_start, src_sorted, dinv, b1, agg100, N_NODES);

    // ---- conv2: xw = h1 @ W2, rowscale dinv -> xws100; gather (postscale dinv) -> h2' (agg100)
    gemm_mfma<1, 1><<<g100, 256, 0, stream>>>(agg100, Wt2, nullptr, dinv, xws100,
        N_NODES, F_IN_DIM, F_IN_PAD, F_IN_DIM, F_IN_PAD, F_IN_PAD, 0, 0);
    gather_kernel<F_IN_DIM, F_IN_PAD, 16, 1><<<gatherBlocks, 256, 0, stream>>>(
        xws100, row_start, src_sorted, dinv, b2, agg100, N_NODES);

    // ---- conv3 (aggregate-first): g = dinv_d*(sum h2' + self) -> xws100; h3 = relu(g@W3+b3) -> big1
    gather_kernel<F_IN_DIM, F_IN_PAD, 16, 2><<<gatherBlocks, 256, 0, stream>>>(
        agg100, row_start, src_sorted, dinv, nullptr, xws100, N_NODES);
    gemm_mfma<1, 1><<<g256, 256, 0, stream>>>(xws100, Wt3, b3, nullptr, big1,
        N_NODES, F_IN_DIM, F_IN_PAD, H_DIM, F_IN_PAD, H_DIM, 1, 0);

    // ---- fc1: 256 -> 256, relu -> big2
    gemm_mfma<1, 1><<<g256, 256, 0, stream>>>(big1, Wtf1, fc1_b, nullptr, big2,
        N_NODES, H_DIM, H_DIM, H_DIM, H_DIM, H_DIM, 1, 0);

    // ---- fc2a: 256 -> 128 -> big1 (bf16, stride 128)
    gemm_mfma<1, 1><<<g100, 256, 0, stream>>>(big2, Wtf2a, fc2ab, nullptr, big1,
        N_NODES, H_DIM, H_DIM, BN_DIM, H_DIM, BN_DIM, 0, 0);

    // ---- BN stats (bf16 input)
    hipMemsetAsync(bn_sum, 0, 2 * 128 * 4, stream);
    bn_stats_kernel<<<512, 256, 0, stream>>>(big1, bn_sum, bn_sumsq, N_NODES);
    bn_finalize_kernel<<<1, 128, 0, stream>>>(bn_sum, bn_sumsq, gamma, beta, bn_a, bn_b, N_NODES);

    // ---- fused BN-apply + fc2b + log_softmax -> out
    fc2b_fused_kernel<<<(N_NODES + 255) / 256, 256, 0, stream>>>(
        big1, bn_a, bn_b, fc2bW, fc2bb, out, N_NODES);
}

// Round 7
// 735.616 us; speedup vs baseline: 15.7354x; 1.0228x over previous
//
#include <hip/hip_runtime.h>
#include <hip/hip_bf16.h>

#define N_NODES 100000
#define N_EDGES 1600000
#define F_IN_DIM 100
#define F_IN_PAD 104     // padded bf16 row stride (13 x 16B chunks)
#define H_DIM 256
#define BN_DIM 128
#define N_LABELS 19
#define BN_EPS 1e-5f

// bucket-partitioned CSR build
#define BUCKET_SHIFT 8
#define NB 391           // ceil(100000 / 256) buckets of 256 nodes
#define EPB 4096         // edges per partition block
#define PB 391           // ceil(1600000 / 4096) partition blocks

typedef __attribute__((ext_vector_type(8))) short bf16x8;   // 4 VGPRs, MFMA A/B frag / 16B
typedef __attribute__((ext_vector_type(4))) short s16x4;    // 8B
typedef __attribute__((ext_vector_type(4))) float f32x4;    // MFMA C/D frag

static __device__ inline short f2bf(float f) {
    __hip_bfloat16 h = __float2bfloat16(f);
    return *(short*)&h;
}
static __device__ inline float bf2f(short s) {
    unsigned u = ((unsigned)(unsigned short)s) << 16;
    return __builtin_bit_cast(float, u);
}

// ---------------------------------------------------------------- CSR build (bucketed)
__global__ __launch_bounds__(256) void part_hist_kernel(const int* __restrict__ dst,
                                                        int* __restrict__ part_hist, int E)
{
    __shared__ int h[NB];
    int tid = threadIdx.x;
    for (int i = tid; i < NB; i += 256) h[i] = 0;
    __syncthreads();
    int base = blockIdx.x * EPB;
    int end = min(base + EPB, E);
    for (int e = base + tid; e < end; e += 256)
        atomicAdd(&h[dst[e] >> BUCKET_SHIFT], 1);
    __syncthreads();
    for (int i = tid; i < NB; i += 256) part_hist[blockIdx.x * NB + i] = h[i];
}

__global__ __launch_bounds__(512) void bucket_total_kernel(const int* __restrict__ part_hist,
                                                           int* __restrict__ bucket_total)
{
    __shared__ int ls[512];
    int b = blockIdx.x;
    int s = 0;
    for (int p = threadIdx.x; p < PB; p += 512) s += part_hist[p * NB + b];
    ls[threadIdx.x] = s;
    __syncthreads();
    for (int off = 256; off > 0; off >>= 1) {
        if (threadIdx.x < off) ls[threadIdx.x] += ls[threadIdx.x + off];
        __syncthreads();
    }
    if (threadIdx.x == 0) bucket_total[b] = ls[0];
}

__global__ __launch_bounds__(512) void bucket_scan_kernel(const int* __restrict__ bucket_total,
                                                          int* __restrict__ bucket_base)
{
    __shared__ int ls[512];
    int tid = threadIdx.x;
    ls[tid] = (tid < NB) ? bucket_total[tid] : 0;
    __syncthreads();
    for (int off = 1; off < 512; off <<= 1) {
        int v = ls[tid];
        int add = (tid >= off) ? ls[tid - off] : 0;
        __syncthreads();
        ls[tid] = v + add;
        __syncthreads();
    }
    if (tid < NB) bucket_base[tid] = (tid > 0) ? ls[tid - 1] : 0;
    if (tid == 0) bucket_base[NB] = ls[NB - 1];
}

__global__ __launch_bounds__(512) void part_offset_kernel(int* __restrict__ part_hist,
                                                          const int* __restrict__ bucket_base)
{
    __shared__ int ls[512];
    int b = blockIdx.x;
    int tid = threadIdx.x;
    int v = (tid < PB) ? part_hist[tid * NB + b] : 0;
    ls[tid] = v;
    __syncthreads();
    for (int off = 1; off < 512; off <<= 1) {
        int x = ls[tid];
        int add = (tid >= off) ? ls[tid - off] : 0;
        __syncthreads();
        ls[tid] = x + add;
        __syncthreads();
    }
    if (tid < PB) part_hist[tid * NB + b] = bucket_base[b] + ((tid > 0) ? ls[tid - 1] : 0);
}

// P2: partition edges into bucket-contiguous packed (src<<8 | dst&255)
__global__ __launch_bounds__(256) void partition_kernel(const int* __restrict__ src,
                                                        const int* __restrict__ dst,
                                                        const int* __restrict__ part_hist,
                                                        int* __restrict__ ep, int E)
{
    __shared__ int cur[NB];
    int tid = threadIdx.x;
    for (int i = tid; i < NB; i += 256) cur[i] = part_hist[blockIdx.x * NB + i];
    __syncthreads();
    int base = blockIdx.x * EPB;
    int end = min(base + EPB, E);
    for (int e = base + tid; e < end; e += 256) {
        int d = dst[e];
        int s = src[e];
        int pos = atomicAdd(&cur[d >> BUCKET_SHIFT], 1);
        ep[pos] = (s << 8) | (d & 255);
    }
}

// P3: per-bucket CSR finish
__global__ __launch_bounds__(256) void bucket_csr_kernel(const int* __restrict__ ep,
                                                         const int* __restrict__ bucket_base,
                                                         int* __restrict__ row_start,
                                                         float* __restrict__ dinv,
                                                         int* __restrict__ src_sorted, int N, int E)
{
    __shared__ int h[256], sc[256], cur[256];
    int b = blockIdx.x;
    int tid = threadIdx.x;
    int e0 = bucket_base[b], e1 = bucket_base[b + 1];
    int node0 = b << BUCKET_SHIFT;
    int nn = min(256, N - node0);

    h[tid] = 0;
    __syncthreads();
    for (int e = e0 + tid; e < e1; e += 256)
        atomicAdd(&h[ep[e] & 255], 1);
    __syncthreads();

    sc[tid] = h[tid];
    __syncthreads();
    for (int off = 1; off < 256; off <<= 1) {
        int v = sc[tid];
        int add = (tid >= off) ? sc[tid - off] : 0;
        __syncthreads();
        sc[tid] = v + add;
        __syncthreads();
    }
    int excl = e0 + ((tid > 0) ? sc[tid - 1] : 0);
    if (tid < nn) {
        row_start[node0 + tid] = excl;
        dinv[node0 + tid] = rsqrtf((float)h[tid] + 1.0f);
    }
    cur[tid] = excl;
    __syncthreads();
    for (int e = e0 + tid; e < e1; e += 256) {
        int p = ep[e];
        int pos = atomicAdd(&cur[p & 255], 1);
        src_sorted[pos] = ((unsigned)p) >> 8;
    }
    if (b == 0 && tid == 0) row_start[N] = E;
}

// ---------------------------------------------------------------- weight pack (all 5 in one)
__global__ __launch_bounds__(256) void pack_all(
    const float* __restrict__ W1, const float* __restrict__ W2, const float* __restrict__ W3,
    const float* __restrict__ Wf1, const float* __restrict__ Wf2a,
    short* __restrict__ Wt1, short* __restrict__ Wt2, short* __restrict__ Wt3,
    short* __restrict__ Wtf1, short* __restrict__ Wtf2a)
{
    int idx = blockIdx.x * 256 + threadIdx.x;
    const float* W; short* Wt; int K, N, Kp, local;
    if (idx < 10400)       { W = W1;   Wt = Wt1;   K = 100; N = 100; Kp = 104; local = idx; }
    else if (idx < 20800)  { W = W2;   Wt = Wt2;   K = 100; N = 100; Kp = 104; local = idx - 10400; }
    else if (idx < 47424)  { W = W3;   Wt = Wt3;   K = 100; N = 256; Kp = 104; local = idx - 20800; }
    else if (idx < 112960) { W = Wf1;  Wt = Wtf1;  K = 256; N = 256; Kp = 256; local = idx - 47424; }
    else if (idx < 145728) { W = Wf2a; Wt = Wtf2a; K = 256; N = 128; Kp = 256; local = idx - 112960; }
    else return;
    int n = local / Kp, k = local - n * Kp;
    Wt[local] = (k < K) ? f2bf(W[(size_t)k * N + n]) : (short)0;
}

// ---------------------------------------------------------------- MFMA GEMM (pipelined, BK=64)
// C[M x Nout] = A[M x K] @ Wt^T  (Wt is [Nout x Kp] bf16, zero-padded)
// Register-prefetch software pipeline: loads for iter i+1 issued before compute(i).
#define SAP 72   // LDS row stride in shorts (144B = 9x16B; 2-way bank conflicts only)
template<int ABF16, int OBF16>
__global__ __launch_bounds__(256) void gemm_mfma(
    const void* __restrict__ Av, const short* __restrict__ Wt,
    const float* __restrict__ bias, const float* __restrict__ rowscale,
    void* __restrict__ Cv, int M, int K, int Kp, int Nout,
    int strideA, int strideC, int relu, int doclip)
{
    __shared__ __align__(16) short As[128][SAP];
    __shared__ __align__(16) short Bs[128][SAP];

    int tid = threadIdx.x;
    int wid = tid >> 6;
    int lane = tid & 63;
    int quad = lane >> 4;
    int l15 = lane & 15;
    int wave_m = (wid & 1) * 64;
    int wave_n = (wid >> 1) * 64;
    int rowBase = blockIdx.y * 128;
    int colBase = blockIdx.x * 128;

    f32x4 acc[4][4];
    #pragma unroll
    for (int i = 0; i < 4; i++)
        #pragma unroll
        for (int j = 0; j < 4; j++)
            acc[i][j] = (f32x4){0.f, 0.f, 0.f, 0.f};

    bf16x8 pa[4];      // bf16 A prefetch regs
    float4 fa[8];      // fp32 A prefetch regs
    bf16x8 pb[4];      // B prefetch regs

    const short* Ab = (const short*)Av;
    const float* Af = (const float*)Av;

    int nIter = (Kp + 63) >> 6;

    // ---- prefetch iter 0
    auto loadA = [&](int k0) {
        if (ABF16) {
            #pragma unroll
            for (int i = 0; i < 4; i++) {
                int ch = tid + i * 256;            // 1024 chunks: 128 rows x 8 (16B)
                int r = ch >> 3, c8 = (ch & 7) << 3;
                int gr = rowBase + r, gk = k0 + c8;
                bf16x8 o = (bf16x8){0,0,0,0,0,0,0,0};
                if (gr < M && gk < strideA)
                    o = *(const bf16x8*)(Ab + (size_t)gr * strideA + gk);
                pa[i] = o;
            }
        } else {
            #pragma unroll
            for (int i = 0; i < 8; i++) {
                int ch = tid + i * 256;            // 2048 chunks: 128 rows x 16 (float4)
                int r = ch >> 4, c4 = (ch & 15) << 2;
                int gr = rowBase + r, gk = k0 + c4;
                float4 v = make_float4(0.f, 0.f, 0.f, 0.f);
                if (gr < M && gk < K)
                    v = *(const float4*)(Af + (size_t)gr * strideA + gk);
                fa[i] = v;
            }
        }
    };
    auto loadB = [&](int k0) {
        #pragma unroll
        for (int i = 0; i < 4; i++) {
            int ch = tid + i * 256;
            int n = ch >> 3, c8 = (ch & 7) << 3;
            int gn = colBase + n, gk = k0 + c8;
            bf16x8 o = (bf16x8){0,0,0,0,0,0,0,0};
            if (gn < Nout && gk < Kp)
                o = *(const bf16x8*)(Wt + (size_t)gn * Kp + gk);
            pb[i] = o;
        }
    };
    auto storeAB = [&]() {
        if (ABF16) {
            #pragma unroll
            for (int i = 0; i < 4; i++) {
                int ch = tid + i * 256;
                int r = ch >> 3, c8 = (ch & 7) << 3;
                *(bf16x8*)(&As[r][c8]) = pa[i];
            }
        } else {
            #pragma unroll
            for (int i = 0; i < 8; i++) {
                int ch = tid + i * 256;
                int r = ch >> 4, c4 = (ch & 15) << 2;
                float4 v = fa[i];
                if (doclip) {
                    v.x = fminf(fmaxf(v.x, -0.4f), 0.4f);
                    v.y = fminf(fmaxf(v.y, -0.4f), 0.4f);
                    v.z = fminf(fmaxf(v.z, -0.4f), 0.4f);
                    v.w = fminf(fmaxf(v.w, -0.4f), 0.4f);
                }
                s16x4 o = (s16x4){f2bf(v.x), f2bf(v.y), f2bf(v.z), f2bf(v.w)};
                *(s16x4*)(&As[r][c4]) = o;
            }
        }
        #pragma unroll
        for (int i = 0; i < 4; i++) {
            int ch = tid + i * 256;
            int n = ch >> 3, c8 = (ch & 7) << 3;
            *(bf16x8*)(&Bs[n][c8]) = pb[i];
        }
    };

    loadA(0); loadB(0);
    for (int it = 0; it < nIter; ++it) {
        if (it > 0) __syncthreads();      // previous compute done reading LDS
        storeAB();                        // implicit vmcnt wait on prefetch regs
        __syncthreads();
        if (it + 1 < nIter) { loadA((it + 1) << 6); loadB((it + 1) << 6); }  // async prefetch
        #pragma unroll
        for (int ks = 0; ks < 2; ks++) {
            bf16x8 a[4], b[4];
            #pragma unroll
            for (int im = 0; im < 4; im++)
                a[im] = *(const bf16x8*)(&As[wave_m + im * 16 + l15][quad * 8 + ks * 32]);
            #pragma unroll
            for (int in = 0; in < 4; in++)
                b[in] = *(const bf16x8*)(&Bs[wave_n + in * 16 + l15][quad * 8 + ks * 32]);
            #pragma unroll
            for (int im = 0; im < 4; im++)
                #pragma unroll
                for (int in = 0; in < 4; in++)
                    acc[im][in] = __builtin_amdgcn_mfma_f32_16x16x32_bf16(
                        a[im], b[in], acc[im][in], 0, 0, 0);
        }
    }

    // ---- epilogue: C/D layout col=lane&15, row=quad*4+reg
    #pragma unroll
    for (int im = 0; im < 4; im++) {
        #pragma unroll
        for (int reg = 0; reg < 4; reg++) {
            int row = rowBase + wave_m + im * 16 + quad * 4 + reg;
            if (row >= M) continue;
            float rs = rowscale ? rowscale[row] : 1.f;
            #pragma unroll
            for (int in = 0; in < 4; in++) {
                int col = colBase + wave_n + in * 16 + l15;
                float v = 0.f;
                if (col < Nout) {
                    v = acc[im][in][reg];
                    if (bias) v += bias[col];
                    v *= rs;
                    if (relu) v = fmaxf(v, 0.f);
                }
                if (OBF16) {
                    if (col < strideC)
                        ((short*)Cv)[(size_t)row * strideC + col] = f2bf(v);
                } else {
                    if (col < Nout)
                        ((float*)Cv)[(size_t)row * strideC + col] = v;
                }
            }
        }
    }
}

// ---------------------------------------------------------------- gather aggregation (bf16)
// acc = sum_{e in in(d)} xws[src[e]]; self = xws[d]; di = dinv[d]
// MODE 0: out = relu(di*(acc+self) + bias)           (conv1)
// MODE 1: out = di * relu(di*(acc+self) + bias)      (conv2: pre-folds next layer's dinv_s)
// MODE 2: out = di * (acc+self)                      (conv3 pre-aggregation)
template<int F, int STRIDE, int T, int MODE>
__global__ void gather_kernel(const short* __restrict__ xws,
                              const int* __restrict__ row_start,
                              const int* __restrict__ src_sorted,
                              const float* __restrict__ dinv,
                              const float* __restrict__ bias,
                              short* __restrict__ out, int n)
{
    constexpr int CHUNKS = STRIDE / 8;
    int group = (blockIdx.x * blockDim.x + threadIdx.x) / T;
    int lane = threadIdx.x % T;
    if (group >= n) return;
    int d = group;
    int e0 = row_start[d], e1 = row_start[d + 1];
    bool active = (lane < CHUNKS);
    int coff = lane * 8;
    float acc[8] = {};
    for (int e = e0; e < e1; e++) {
        int s = src_sorted[e];
        if (active) {
            bf16x8 v = *(const bf16x8*)(xws + (size_t)s * STRIDE + coff);
            #pragma unroll
            for (int j = 0; j < 8; j++) acc[j] += bf2f(v[j]);
        }
    }
    if (active) {
        bf16x8 xv = *(const bf16x8*)(xws + (size_t)d * STRIDE + coff);
        float di = dinv[d];
        bf16x8 o;
        #pragma unroll
        for (int j = 0; j < 8; j++) {
            int col = coff + j;
            float v = 0.f;
            if (col < F) {
                v = di * (acc[j] + bf2f(xv[j]));
                if (MODE == 0) v = fmaxf(v + bias[col], 0.f);
                if (MODE == 1) v = di * fmaxf(v + bias[col], 0.f);
            }
            o[j] = f2bf(v);
        }
        *(bf16x8*)(out + (size_t)d * STRIDE + coff) = o;
    }
}

// ---------------------------------------------------------------- BN stats (bf16 input)
__global__ void bn_stats_kernel(const short* __restrict__ h,
                                float* __restrict__ sum, float* __restrict__ sumsq, int Ntot)
{
    int c = threadIdx.x & 127;
    int rpb = blockDim.x >> 7;
    int r0 = blockIdx.x * rpb + (threadIdx.x >> 7);
    int stride = gridDim.x * rpb;
    float s = 0.f, ss = 0.f;
    for (int r = r0; r < Ntot; r += stride) {
        float v = bf2f(h[(size_t)r * BN_DIM + c]);
        s += v; ss += v * v;
    }
    __shared__ float ls[256], lss[256];
    ls[threadIdx.x] = s; lss[threadIdx.x] = ss;
    __syncthreads();
    if (threadIdx.x < 128) {
        s = ls[threadIdx.x] + ls[threadIdx.x + 128];
        ss = lss[threadIdx.x] + lss[threadIdx.x + 128];
        atomicAdd(&sum[c], s);
        atomicAdd(&sumsq[c], ss);
    }
}

__global__ void bn_finalize_kernel(const float* __restrict__ sum, const float* __restrict__ sumsq,
                                   const float* __restrict__ gamma, const float* __restrict__ beta,
                                   float* __restrict__ a, float* __restrict__ b, int Ntot)
{
    int c = threadIdx.x;
    float inv_n = 1.0f / (float)Ntot;
    float mu = sum[c] * inv_n;
    float var = sumsq[c] * inv_n - mu * mu;
    float ai = gamma[c] * rsqrtf(var + BN_EPS);
    a[c] = ai;
    b[c] = beta[c] - mu * ai;
}

// ---------------------------------------------------------------- fused BN-apply + fc2b + log_softmax
__global__ __launch_bounds__(256) void fc2b_fused_kernel(
    const short* __restrict__ h, const float* __restrict__ bn_a, const float* __restrict__ bn_b,
    const float* __restrict__ W, const float* __restrict__ bias,
    float* __restrict__ out, int Ntot)
{
    __shared__ float Ws[BN_DIM][N_LABELS + 1];
    __shared__ float as[BN_DIM], bs[BN_DIM];
    for (int i = threadIdx.x; i < BN_DIM * N_LABELS; i += 256) {
        int k = i / N_LABELS, j = i - k * N_LABELS;
        Ws[k][j] = W[i];
    }
    if (threadIdx.x < BN_DIM) {
        as[threadIdx.x] = bn_a[threadIdx.x];
        bs[threadIdx.x] = bn_b[threadIdx.x];
    }
    __syncthreads();

    int r = blockIdx.x * 256 + threadIdx.x;
    if (r >= Ntot) return;

    float acc[N_LABELS];
    #pragma unroll
    for (int j = 0; j < N_LABELS; j++) acc[j] = bias[j];

    const short* hr = h + (size_t)r * BN_DIM;
    #pragma unroll
    for (int k0 = 0; k0 < BN_DIM; k0 += 8) {
        bf16x8 hv = *(const bf16x8*)(hr + k0);
        #pragma unroll
        for (int t = 0; t < 8; t++) {
            float v = fmaxf(bf2f(hv[t]) * as[k0 + t] + bs[k0 + t], 0.f);
            #pragma unroll
            for (int j = 0; j < N_LABELS; j++)
                acc[j] = fmaf(v, Ws[k0 + t][j], acc[j]);
        }
    }

    float m = acc[0];
    #pragma unroll
    for (int j = 1; j < N_LABELS; j++) m = fmaxf(m, acc[j]);
    float s = 0.f;
    #pragma unroll
    for (int j = 0; j < N_LABELS; j++) s += expf(acc[j] - m);
    float lse = m + logf(s);
    float* o = out + (size_t)r * N_LABELS;
    #pragma unroll
    for (int j = 0; j < N_LABELS; j++) o[j] = acc[j] - lse;
}

// ================================================================ launch
extern "C" void kernel_launch(void* const* d_in, const int* in_sizes, int n_in,
                              void* d_out, int out_size, void* d_ws, size_t ws_size,
                              hipStream_t stream)
{
    const float* x      = (const float*)d_in[0];
    const int*   ei     = (const int*)d_in[1];
    const float* W1     = (const float*)d_in[2];
    const float* b1     = (const float*)d_in[3];
    const float* W2     = (const float*)d_in[4];
    const float* b2     = (const float*)d_in[5];
    const float* W3     = (const float*)d_in[6];
    const float* b3     = (const float*)d_in[7];
    const float* fc1_W  = (const float*)d_in[8];
    const float* fc1_b  = (const float*)d_in[9];
    const float* fc2aW  = (const float*)d_in[10];
    const float* fc2ab  = (const float*)d_in[11];
    const float* gamma  = (const float*)d_in[12];
    const float* beta   = (const float*)d_in[13];
    const float* fc2bW  = (const float*)d_in[14];
    const float* fc2bb  = (const float*)d_in[15];
    float* out = (float*)d_out;

    const int* src = ei;
    const int* dst = ei + N_EDGES;

    char* w = (char*)d_ws;
    float* dinv        = (float*)w;  w += ((size_t)N_NODES * 4 + 255) / 256 * 256;
    int*   row_start   = (int*)w;    w += ((size_t)(N_NODES + 1) * 4 + 255) / 256 * 256;
    int*   part_hist   = (int*)w;    w += ((size_t)PB * NB * 4 + 255) / 256 * 256;
    int*   bucket_total= (int*)w;    w += ((size_t)NB * 4 + 255) / 256 * 256;
    int*   bucket_base = (int*)w;    w += ((size_t)(NB + 1) * 4 + 255) / 256 * 256;
    float* bn_sum      = (float*)w;  w += 128 * 4;
    float* bn_sumsq    = (float*)w;  w += 128 * 4;
    float* bn_a        = (float*)w;  w += 128 * 4;
    float* bn_b        = (float*)w;  w += 128 * 4;
    short* Wt1         = (short*)w;  w += ((size_t)F_IN_DIM * F_IN_PAD * 2 + 255) / 256 * 256;
    short* Wt2         = (short*)w;  w += ((size_t)F_IN_DIM * F_IN_PAD * 2 + 255) / 256 * 256;
    short* Wt3         = (short*)w;  w += ((size_t)H_DIM * F_IN_PAD * 2 + 255) / 256 * 256;
    short* Wtf1        = (short*)w;  w += ((size_t)H_DIM * H_DIM * 2 + 255) / 256 * 256;
    short* Wtf2a       = (short*)w;  w += ((size_t)BN_DIM * H_DIM * 2 + 255) / 256 * 256;
    int*   src_sorted  = (int*)w;    w += ((size_t)N_EDGES * 4 + 255) / 256 * 256;
    int*   ep          = (int*)w;    w += ((size_t)N_EDGES * 4 + 255) / 256 * 256;
    short* xws100      = (short*)w;  w += ((size_t)N_NODES * F_IN_PAD * 2 + 255) / 256 * 256;
    short* agg100      = (short*)w;  w += ((size_t)N_NODES * F_IN_PAD * 2 + 255) / 256 * 256;
    short* big1        = (short*)w;  w += ((size_t)N_NODES * H_DIM * 2 + 255) / 256 * 256;
    short* big2        = (short*)w;  w += ((size_t)N_NODES * H_DIM * 2 + 255) / 256 * 256;

    // ---- CSR build (bucket-partitioned, LDS atomics) + dinv
    part_hist_kernel<<<PB, 256, 0, stream>>>(dst, part_hist, N_EDGES);
    bucket_total_kernel<<<NB, 512, 0, stream>>>(part_hist, bucket_total);
    bucket_scan_kernel<<<1, 512, 0, stream>>>(bucket_total, bucket_base);
    part_offset_kernel<<<NB, 512, 0, stream>>>(part_hist, bucket_base);
    partition_kernel<<<PB, 256, 0, stream>>>(src, dst, part_hist, ep, N_EDGES);
    bucket_csr_kernel<<<NB, 256, 0, stream>>>(ep, bucket_base, row_start, dinv,
                                              src_sorted, N_NODES, N_EDGES);

    // ---- pack weights (transpose + bf16 + zero-pad K), single launch
    pack_all<<<570, 256, 0, stream>>>(W1, W2, W3, fc1_W, fc2aW, Wt1, Wt2, Wt3, Wtf1, Wtf2a);

    dim3 g100(1, (N_NODES + 127) / 128);
    dim3 g256(2, (N_NODES + 127) / 128);
    int gatherBlocks = (N_NODES * 16 + 255) / 256;

    // ---- conv1: xw = clip(x) @ W1, rowscale dinv -> xws100; gather -> h1 (agg100)
    gemm_mfma<0, 1><<<g100, 256, 0, stream>>>(x, Wt1, nullptr, dinv, xws100,
        N_NODES, F_IN_DIM, F_IN_PAD, F_IN_DIM, F_IN_DIM, F_IN_PAD, 0, 1);
    gather_kernel<F_IN_DIM, F_IN_PAD, 16, 0><<<gatherBlocks, 256, 0, stream>>>(
        xws100, row_start, src_sorted, dinv, b1, agg100, N_NODES);

    // ---- conv2: xw = h1 @ W2, rowscale dinv -> xws100; gather (postscale dinv) -> h2' (agg100)
    gemm_mfma<1, 1><<<g100, 256, 0, stream>>>(agg100, Wt2, nullptr, dinv, xws100,
        N_NODES, F_IN_DIM, F_IN_PAD, F_IN_DIM, F_IN_PAD, F_IN_PAD, 0, 0);
    gather_kernel<F_IN_DIM, F_IN_PAD, 16, 1><<<gatherBlocks, 256, 0, stream>>>(
        xws100, row_start, src_sorted, dinv, b2, agg100, N_NODES);

    // ---- conv3 (aggregate-first): g = dinv_d*(sum h2' + self) -> xws100; h3 = relu(g@W3+b3) -> big1
    gather_kernel<F_IN_DIM, F_IN_PAD, 16, 2><<<gatherBlocks, 256, 0, stream>>>(
        agg100, row_start, src_sorted, dinv, nullptr, xws100, N_NODES);
    gemm_mfma<1, 1><<<g256, 256, 0, stream>>>(xws100, Wt3, b3, nullptr, big1,
        N_NODES, F_IN_DIM, F_IN_PAD, H_DIM, F_IN_PAD, H_DIM, 1, 0);

    // ---- fc1: 256 -> 256, relu -> big2
    gemm_mfma<1, 1><<<g256, 256, 0, stream>>>(big1, Wtf1, fc1_b, nullptr, big2,
        N_NODES, H_DIM, H_DIM, H_DIM, H_DIM, H_DIM, 1, 0);

    // ---- fc2a: 256 -> 128 -> big1 (bf16, stride 128)
    gemm_mfma<1, 1><<<g100, 256, 0, stream>>>(big2, Wtf2a, fc2ab, nullptr, big1,
        N_NODES, H_DIM, H_DIM, BN_DIM, H_DIM, BN_DIM, 0, 0);

    // ---- BN stats (bf16 input)
    hipMemsetAsync(bn_sum, 0, 2 * 128 * 4, stream);
    bn_stats_kernel<<<512, 256, 0, stream>>>(big1, bn_sum, bn_sumsq, N_NODES);
    bn_finalize_kernel<<<1, 128, 0, stream>>>(bn_sum, bn_sumsq, gamma, beta, bn_a, bn_b, N_NODES);

    // ---- fused BN-apply + fc2b + log_softmax -> out
    fc2b_fused_kernel<<<(N_NODES + 255) / 256, 256, 0, stream>>>(
        big1, bn_a, bn_b, fc2bW, fc2bb, out, N_NODES);
}